// Round 4
// baseline (5234.839 us; speedup 1.0000x reference)
//
#include <hip/hip_runtime.h>

typedef __attribute__((ext_vector_type(8))) short short8;
typedef __attribute__((ext_vector_type(4))) float f32x4;
union U16x8 { uint4 u4; short8 s8; };

__device__ inline float bf2f(unsigned short u){
  unsigned int x = ((unsigned int)u) << 16;
  float f; __builtin_memcpy(&f, &x, 4); return f;
}
__device__ inline unsigned short f2bf(float f){
  unsigned int x; __builtin_memcpy(&x, &f, 4);
  x = x + 0x7FFFu + ((x >> 16) & 1u);
  return (unsigned short)(x >> 16);
}
__device__ inline void split4(float4 f, uint2& hi, uint2& lo){
  unsigned short h0=f2bf(f.x), h1=f2bf(f.y), h2=f2bf(f.z), h3=f2bf(f.w);
  unsigned short l0=f2bf(f.x-bf2f(h0)), l1=f2bf(f.y-bf2f(h1)),
                 l2=f2bf(f.z-bf2f(h2)), l3=f2bf(f.w-bf2f(h3));
  hi = (uint2){(unsigned)h0 | ((unsigned)h1<<16), (unsigned)h2 | ((unsigned)h3<<16)};
  lo = (uint2){(unsigned)l0 | ((unsigned)l1<<16), (unsigned)l2 | ((unsigned)l3<<16)};
}
__device__ inline void split8(float4 f0, float4 f1, uint4& hi, uint4& lo){
  uint2 h0,l0,h1,l1; split4(f0,h0,l0); split4(f1,h1,l1);
  hi = (uint4){h0.x,h0.y,h1.x,h1.y};
  lo = (uint4){l0.x,l0.y,l1.x,l1.y};
}

#define MFMA16(a,b,c) __builtin_amdgcn_mfma_f32_16x16x32_bf16((a).s8,(b).s8,(c),0,0,0)

// device-scope (sc1) fine-grained ops — cross-XCD coherent without cache flushes
__device__ inline void st_f32_sc(float* p, float v){
  __hip_atomic_store(p, v, __ATOMIC_RELAXED, __HIP_MEMORY_SCOPE_AGENT);
}
__device__ inline void st_u32_sc(unsigned int* p, unsigned int v){
  __hip_atomic_store(p, v, __ATOMIC_RELAXED, __HIP_MEMORY_SCOPE_AGENT);
}
__device__ inline unsigned long long ld_u64_sc(const unsigned long long* p){
  return __hip_atomic_load(p, __ATOMIC_RELAXED, __HIP_MEMORY_SCOPE_AGENT);
}
// L2-cacheable load (sc0 bypasses L1; NO sc1 -> allocates in this XCD's L2).
// Freshness is guaranteed by the per-step agent-acquire fence (buffer_inv sc1).
__device__ inline uint4 ld_b128_l2(const unsigned short* p){
  uint4 r;
  asm volatile("global_load_dwordx4 %0, %1, off sc0"
               : "=&v"(r) : "v"(p) : "memory");
  return r;
}
__device__ inline void wait_vm0(){ asm volatile("s_waitcnt vmcnt(0)" ::: "memory"); }

__global__ __launch_bounds__(256)
void split_fp32(const float* __restrict__ x,
                unsigned short* __restrict__ hi,
                unsigned short* __restrict__ lo, int n4){
  int i = blockIdx.x * 256 + threadIdx.x;
  if (i >= n4) return;
  float4 v = ((const float4*)x)[i];
  ushort4 h, l;
  h.x = f2bf(v.x); l.x = f2bf(v.x - bf2f(h.x));
  h.y = f2bf(v.y); l.y = f2bf(v.y - bf2f(h.y));
  h.z = f2bf(v.z); l.z = f2bf(v.z - bf2f(h.z));
  h.w = f2bf(v.w); l.w = f2bf(v.w - bf2f(h.w));
  ((ushort4*)hi)[i] = h;
  ((ushort4*)lo)[i] = l;
}

// h0 = p0(64x512) @ Winit(4096x512)^T, 3-term. Writes h in SWIZZLED global layout.
__global__ __launch_bounds__(512, 2)
void h0_mm(const float* __restrict__ p0,
           const float* __restrict__ Wini,
           unsigned short* __restrict__ oHi,
           unsigned short* __restrict__ oLo)
{
  const int nb = blockIdx.x;
  const int tid = threadIdx.x, lane = tid & 63, wave = tid >> 6;
  const int quad = lane >> 4, l16 = lane & 15;
  const int mw = wave & 3, nw = wave >> 2;
  __shared__ __attribute__((aligned(16))) unsigned short BH[128*40];
  __shared__ __attribute__((aligned(16))) unsigned short BL[128*40];
  const int srow = tid >> 2, sk = (tid & 3) << 3;
  const float* wp = Wini + (size_t)(nb*128 + srow)*512 + sk;
  const float* ap = p0 + (size_t)(mw*16 + l16)*512 + quad*8;
  f32x4 acc[4];
  #pragma unroll
  for (int tn = 0; tn < 4; ++tn) acc[tn] = (f32x4){0.f,0.f,0.f,0.f};
  for (int kc = 0; kc < 16; ++kc){
    float4 f0 = *(const float4*)(wp + kc*32);
    float4 f1 = *(const float4*)(wp + kc*32 + 4);
    uint4 hi, lo; split8(f0, f1, hi, lo);
    __syncthreads();
    *(uint4*)&BH[srow*40 + sk] = hi;
    *(uint4*)&BL[srow*40 + sk] = lo;
    __syncthreads();
    float4 a0 = *(const float4*)(ap + kc*32);
    float4 a1 = *(const float4*)(ap + kc*32 + 4);
    uint4 ahi, alo; split8(a0, a1, ahi, alo);
    U16x8 aU, lU; aU.u4 = ahi; lU.u4 = alo;
    #pragma unroll
    for (int tn = 0; tn < 4; ++tn){
      U16x8 bh, bl;
      const int off = (nw*64 + tn*16 + l16)*40 + quad*8;
      bh.u4 = *(const uint4*)&BH[off];
      bl.u4 = *(const uint4*)&BL[off];
      acc[tn] = MFMA16(aU, bh, acc[tn]);
      acc[tn] = MFMA16(aU, bl, acc[tn]);
      acc[tn] = MFMA16(lU, bh, acc[tn]);
    }
  }
  #pragma unroll
  for (int tn = 0; tn < 4; ++tn){
    const int n = nb*128 + nw*64 + tn*16 + l16;
    #pragma unroll
    for (int r = 0; r < 4; ++r){
      const int row = mw*16 + quad*4 + r;
      const int g = n >> 3, gp = (g & ~7) | ((g & 7) ^ (row & 7));
      const int np = (gp << 3) | (n & 7);
      float val = acc[tn][r];
      unsigned short hh = f2bf(val);
      oHi[(size_t)row*4096 + np] = hh;
      oLo[(size_t)row*4096 + np] = f2bf(val - bf2f(hh));
    }
  }
}

// Persistent RNN: 256 blocks (kb=bx&7, nb=bx>>3) x 512 thr. W hi/lo in VGPRs.
// r4 delta vs r0 (verified 3618us): stage loads are L2-cacheable (sc0 only) so
// the ~32 same-kb blocks (one XCD under round-robin) share one LLC fetch of the
// h k-slice instead of 32 sc1 fetches; a per-step agent-acquire fence
// (buffer_inv sc1) invalidates the XCD L2 after bar2 so re-reads are fresh.
// All kernel stores are sc1 (G store switched from nontemporal) so L2 never
// holds dirty lines and the invalidate is trivially safe.
__global__ __launch_bounds__(512, 2)
void rnn_persist(const float* __restrict__ W,
                 const float* __restrict__ v,
                 const float* __restrict__ Wih,
                 unsigned short* __restrict__ hHiA,
                 unsigned short* __restrict__ hLoA,
                 unsigned short* __restrict__ hHiB,
                 unsigned short* __restrict__ hLoB,
                 float* __restrict__ part,
                 unsigned int* __restrict__ bar,
                 unsigned short* __restrict__ G)
{
  const int bx = blockIdx.x, kb = bx & 7, nb = bx >> 3;
  const int tid = threadIdx.x, lane = tid & 63, wave = tid >> 6;
  const int quad = lane >> 4, l16 = lane & 15;
  __shared__ __attribute__((aligned(16))) unsigned short AH[64*512];  // 64 KB
  __shared__ __attribute__((aligned(16))) unsigned short AL[64*512];  // 64 KB

  unsigned int* sub1 = bar;          // [128][8]
  unsigned int* root1 = bar + 1024;  // [128]
  unsigned int* sub2 = bar + 2048;   // [128][8]
  unsigned int* root2 = bar + 3072;  // [128]

  // W slice -> registers: wave owns 16 cols (nb*128 + wave*16 + l16), k-slice kb*512
  uint4 whi[16], wlo[16];
  {
    const float* wp = W + (size_t)(nb*128 + wave*16 + l16)*4096 + kb*512 + quad*8;
    #pragma unroll
    for (int c = 0; c < 16; ++c){
      float4 f0 = *(const float4*)(wp + c*32);
      float4 f1 = *(const float4*)(wp + c*32 + 4);
      split8(f0, f1, whi[c], wlo[c]);
    }
  }

  const int redM = bx >> 2;
  const int nbase = ((bx & 3) << 10) + (tid << 1);

  for (int s = 0; s < 128; ++s){
    const unsigned short* hH = (s & 1) ? hHiB : hHiA;
    const unsigned short* hL = (s & 1) ? hLoB : hLoA;
    unsigned short* nHi = (s & 1) ? hHiA : hHiB;
    unsigned short* nLo = (s & 1) ? hLoA : hLoB;

    // ---- invalidate local L2 (clean lines only exist) so stage reads are fresh
    __builtin_amdgcn_fence(__ATOMIC_ACQUIRE, "agent");

    // ---- stage h k-slice (swizzled-global verbatim copy), L2-cacheable ----
    {
      uint4 stg[16];
      #pragma unroll
      for (int i = 0; i < 8; ++i){
        const int flat = tid + i*512, row = flat >> 6, g = flat & 63;
        stg[i] = ld_b128_l2(hH + (size_t)row*4096 + (kb << 9) + g*8);
      }
      #pragma unroll
      for (int i = 0; i < 8; ++i){
        const int flat = tid + i*512, row = flat >> 6, g = flat & 63;
        stg[8 + i] = ld_b128_l2(hL + (size_t)row*4096 + (kb << 9) + g*8);
      }
      asm volatile("s_waitcnt vmcnt(8)" ::: "memory");
      #pragma unroll
      for (int i = 0; i < 8; ++i){
        const int flat = tid + i*512, row = flat >> 6, g = flat & 63;
        *(uint4*)&AH[row*512 + g*8] = stg[i];
      }
      asm volatile("s_waitcnt vmcnt(0)" ::: "memory");
      #pragma unroll
      for (int i = 0; i < 8; ++i){
        const int flat = tid + i*512, row = flat >> 6, g = flat & 63;
        *(uint4*)&AL[row*512 + g*8] = stg[8 + i];
      }
    }
    __syncthreads();

    // ---- MFMA: 16 k-chunks x 4 m-tiles x 3 terms ----
    f32x4 acc[4];
    #pragma unroll
    for (int mt = 0; mt < 4; ++mt) acc[mt] = (f32x4){0.f,0.f,0.f,0.f};
    #pragma unroll
    for (int c = 0; c < 16; ++c){
      U16x8 bh, bl; bh.u4 = whi[c]; bl.u4 = wlo[c];
      #pragma unroll
      for (int mt = 0; mt < 4; ++mt){
        const int row = mt*16 + l16;
        const int gk = c*4 + quad;
        const int phys = (gk & 56) | ((gk & 7) ^ (row & 7));
        U16x8 ah, al;
        ah.u4 = *(const uint4*)&AH[row*512 + phys*8];
        al.u4 = *(const uint4*)&AL[row*512 + phys*8];
        acc[mt] = MFMA16(ah, bh, acc[mt]);
        acc[mt] = MFMA16(ah, bl, acc[mt]);
        acc[mt] = MFMA16(al, bh, acc[mt]);
      }
    }

    // ---- partial store (sc1 write-through): tile layout [bx][w][m][c16] ----
    {
      float* pb = part + (size_t)bx*8192 + wave*1024 + l16;
      #pragma unroll
      for (int mt = 0; mt < 4; ++mt)
        #pragma unroll
        for (int r = 0; r < 4; ++r)
          st_f32_sc(pb + (mt*16 + quad*4 + r)*16, acc[mt][r]);
    }
    wait_vm0();
    __syncthreads();
    if (tid == 0){
      if (atomicAdd(&sub1[s*8 + kb], 1u) == 31u) atomicAdd(&root1[s], 1u);
      while (__hip_atomic_load(&root1[s], __ATOMIC_RELAXED, __HIP_MEMORY_SCOPE_AGENT) < 8u)
        __builtin_amdgcn_s_sleep(1);
    }
    __syncthreads();

    // ---- distributed reduce: 2 elems/thread (row redM, cols nbase, nbase+1) ----
    {
      float2 sum = {0.f, 0.f};
      const size_t off = (size_t)((nbase >> 4) & 7)*1024 + redM*16 + (nbase & 15);
      #pragma unroll
      for (int k2 = 0; k2 < 8; ++k2){
        unsigned long long q = ld_u64_sc((const unsigned long long*)
            (part + (size_t)((nbase >> 7)*8 + k2)*8192 + off));
        float2 p; __builtin_memcpy(&p, &q, 8);
        sum.x += p.x; sum.y += p.y;
      }
      const float2 vv = *(const float2*)(v + ((size_t)redM*128 + s)*2);
      const float4 wi = *(const float4*)(Wih + (size_t)nbase*2);
      float v0 = fmaxf(sum.x + vv.x*wi.x + vv.y*wi.y, 0.f);
      float v1 = fmaxf(sum.y + vv.x*wi.z + vv.y*wi.w, 0.f);
      const unsigned short h0 = f2bf(v0), h1 = f2bf(v1);
      const unsigned short q0 = f2bf(v0 - bf2f(h0)), q1 = f2bf(v1 - bf2f(h1));
      const int g = nbase >> 3, gp = (g & ~7) | ((g & 7) ^ (redM & 7));
      const int np = (gp << 3) | (nbase & 7);
      st_u32_sc((unsigned int*)(nHi + (size_t)redM*4096 + np),
                (unsigned)h0 | ((unsigned)h1 << 16));
      st_u32_sc((unsigned int*)(nLo + (size_t)redM*4096 + np),
                (unsigned)q0 | ((unsigned)q1 << 16));
      st_u32_sc((unsigned int*)(G + (size_t)s*262144 + (size_t)redM*4096 + nbase),
                (unsigned)h0 | ((unsigned)h1 << 16));
    }
    wait_vm0();
    __syncthreads();
    if (tid == 0){
      if (atomicAdd(&sub2[s*8 + kb], 1u) == 31u) atomicAdd(&root2[s], 1u);
      while (__hip_atomic_load(&root2[s], __ATOMIC_RELAXED, __HIP_MEMORY_SCOPE_AGENT) < 8u)
        __builtin_amdgcn_s_sleep(1);
    }
    __syncthreads();
  }
}

// out = G(8192 x 4096, hi-only) @ Wdec(512x4096)^T, 2-term (pre-split bf16).
__global__ __launch_bounds__(256, 1)
void decode_g(const unsigned short* __restrict__ G,
              const unsigned short* __restrict__ WdH,
              const unsigned short* __restrict__ WdL,
              float* __restrict__ out)
{
  const int tid = threadIdx.x, lane = tid & 63, wave = tid >> 6;
  const int quad = lane >> 4, l16 = lane & 15;
  const int wm = wave & 1, wn = wave >> 1;
  const int m0 = blockIdx.x * 128;
  const int n0 = blockIdx.y * 128;
  __shared__ __attribute__((aligned(16))) unsigned short BH[2][128*64];
  __shared__ __attribute__((aligned(16))) unsigned short BL[2][128*64];

  const unsigned short* gp[4];
  #pragma unroll
  for (int tm = 0; tm < 4; ++tm)
    gp[tm] = G + (size_t)(m0 + wm*64 + tm*16 + l16)*4096 + quad*8;

  #define LD_B(c, h4, l4) { _Pragma("unroll") \
    for (int i = 0; i < 4; ++i){ const int q = tid + i*256, row = q >> 3, gk = q & 7; \
      const size_t so = (size_t)(n0 + row)*4096 + (size_t)(c)*64 + gk*8; \
      (h4)[i] = *(const uint4*)(WdH + so); (l4)[i] = *(const uint4*)(WdL + so); } }
  #define ST_B(buf, h4, l4) { _Pragma("unroll") \
    for (int i = 0; i < 4; ++i){ const int q = tid + i*256, row = q >> 3, gk = q & 7; \
      const int phys = gk ^ (row & 7); \
      *(uint4*)&BH[buf][row*64 + phys*8] = (h4)[i]; \
      *(uint4*)&BL[buf][row*64 + phys*8] = (l4)[i]; } }
  #define LD_A(c, dst) { _Pragma("unroll") \
    for (int tm = 0; tm < 4; ++tm){ _Pragma("unroll") \
      for (int ks = 0; ks < 2; ++ks) \
        (dst)[tm][ks] = *(const uint4*)(gp[tm] + (size_t)(c)*64 + ks*32); } }

  f32x4 acc[4][4];
  #pragma unroll
  for (int a = 0; a < 4; ++a)
    #pragma unroll
    for (int b = 0; b < 4; ++b) acc[a][b] = (f32x4){0.f,0.f,0.f,0.f};

  uint4 pbh[4], pbl[4];
  uint4 ar[2][4][2];
  LD_B(0, pbh, pbl); ST_B(0, pbh, pbl);
  LD_A(0, ar[0]);
  LD_A(1, ar[1]);
  LD_B(1, pbh, pbl);
  __syncthreads();

  for (int c = 0; c < 64; ++c){
    const int cur = c & 1;
    #pragma unroll
    for (int ks = 0; ks < 2; ++ks){
      U16x8 bh[4], bl[4];
      #pragma unroll
      for (int tn = 0; tn < 4; ++tn){
        const int row = wn*64 + tn*16 + l16;
        const int gk = ks*4 + quad;
        const int phys = gk ^ (row & 7);
        bh[tn].u4 = *(const uint4*)&BH[cur][row*64 + phys*8];
        bl[tn].u4 = *(const uint4*)&BL[cur][row*64 + phys*8];
      }
      #pragma unroll
      for (int tm = 0; tm < 4; ++tm){
        U16x8 a; a.u4 = ar[cur][tm][ks];
        #pragma unroll
        for (int tn = 0; tn < 4; ++tn){
          acc[tm][tn] = MFMA16(a, bh[tn], acc[tm][tn]);
          acc[tm][tn] = MFMA16(a, bl[tn], acc[tm][tn]);
        }
      }
    }
    if (c + 2 < 64) LD_A(c+2, ar[cur]);
    if (c + 1 < 64){
      ST_B(cur ^ 1, pbh, pbl);
      if (c + 2 < 64) LD_B(c+2, pbh, pbl);
      __syncthreads();
    }
  }
  #pragma unroll
  for (int tm = 0; tm < 4; ++tm){
    #pragma unroll
    for (int tn = 0; tn < 4; ++tn){
      const int p = n0 + wn*64 + tn*16 + l16;
      #pragma unroll
      for (int r = 0; r < 4; ++r){
        const int rm = m0 + wm*64 + tm*16 + quad*4 + r;
        out[((size_t)(rm & 63)*128 + (rm >> 6))*512 + p] = acc[tm][tn][r];
      }
    }
  }
}

extern "C" void kernel_launch(void* const* d_in, const int* in_sizes, int n_in,
                              void* d_out, int out_size, void* d_ws, size_t ws_size,
                              hipStream_t stream) {
  const float* v    = (const float*)d_in[0];
  const float* p0   = (const float*)d_in[1];
  const float* Wini = (const float*)d_in[2];
  const float* Wih  = (const float*)d_in[3];
  const float* Whh  = (const float*)d_in[4];
  const float* Wdec = (const float*)d_in[5];
  float* out = (float*)d_out;
  char* wsb = (char*)d_ws;

  // ws layout (bytes)
  unsigned int*   bar  = (unsigned int*)(wsb + 0);          // 16 KB
  unsigned short* hHiA = (unsigned short*)(wsb + 16384);
  unsigned short* hLoA = (unsigned short*)(wsb + 540672);
  unsigned short* hHiB = (unsigned short*)(wsb + 1064960);
  unsigned short* hLoB = (unsigned short*)(wsb + 1589248);
  float*          part = (float*)(wsb + 2113536);           // 8 MB
  unsigned short* WdH  = (unsigned short*)(wsb + 10502144); // 4 MB
  unsigned short* WdL  = (unsigned short*)(wsb + 14696448); // 4 MB
  unsigned short* G    = (unsigned short*)(wsb + 18890752); // 64 MB
  // end ~86.0 MB

  hipMemsetAsync(bar, 0, 16384, stream);
  split_fp32<<<dim3(2048), dim3(256), 0, stream>>>(Wdec, WdH, WdL, 524288);
  h0_mm<<<dim3(32), dim3(512), 0, stream>>>(p0, Wini, hHiA, hLoA);
  rnn_persist<<<dim3(256), dim3(512), 0, stream>>>(Whh, v, Wih,
                                                   hHiA, hLoA, hHiB, hLoB,
                                                   part, bar, G);
  decode_g<<<dim3(64, 4), dim3(256), 0, stream>>>(G, WdH, WdL, out);
}

// Round 5
// 2672.145 us; speedup vs baseline: 1.9590x; 1.9590x over previous
//
#include <hip/hip_runtime.h>

typedef __attribute__((ext_vector_type(8))) short short8;
typedef __attribute__((ext_vector_type(4))) float f32x4;
union U16x8 { uint4 u4; short8 s8; };

__device__ inline float bf2f(unsigned short u){
  unsigned int x = ((unsigned int)u) << 16;
  float f; __builtin_memcpy(&f, &x, 4); return f;
}
__device__ inline unsigned short f2bf(float f){
  unsigned int x; __builtin_memcpy(&x, &f, 4);
  x = x + 0x7FFFu + ((x >> 16) & 1u);
  return (unsigned short)(x >> 16);
}
__device__ inline void split4(float4 f, uint2& hi, uint2& lo){
  unsigned short h0=f2bf(f.x), h1=f2bf(f.y), h2=f2bf(f.z), h3=f2bf(f.w);
  unsigned short l0=f2bf(f.x-bf2f(h0)), l1=f2bf(f.y-bf2f(h1)),
                 l2=f2bf(f.z-bf2f(h2)), l3=f2bf(f.w-bf2f(h3));
  hi = (uint2){(unsigned)h0 | ((unsigned)h1<<16), (unsigned)h2 | ((unsigned)h3<<16)};
  lo = (uint2){(unsigned)l0 | ((unsigned)l1<<16), (unsigned)l2 | ((unsigned)l3<<16)};
}
__device__ inline void split8(float4 f0, float4 f1, uint4& hi, uint4& lo){
  uint2 h0,l0,h1,l1; split4(f0,h0,l0); split4(f1,h1,l1);
  hi = (uint4){h0.x,h0.y,h1.x,h1.y};
  lo = (uint4){l0.x,l0.y,l1.x,l1.y};
}

#define MFMA16(a,b,c) __builtin_amdgcn_mfma_f32_16x16x32_bf16((a).s8,(b).s8,(c),0,0,0)

// device-scope (sc1) fine-grained ops — cross-XCD coherent without cache flushes
__device__ inline void st_f32_sc(float* p, float v){
  __hip_atomic_store(p, v, __ATOMIC_RELAXED, __HIP_MEMORY_SCOPE_AGENT);
}
__device__ inline void st_u32_sc(unsigned int* p, unsigned int v){
  __hip_atomic_store(p, v, __ATOMIC_RELAXED, __HIP_MEMORY_SCOPE_AGENT);
}
__device__ inline unsigned long long ld_u64_sc(const unsigned long long* p){
  return __hip_atomic_load(p, __ATOMIC_RELAXED, __HIP_MEMORY_SCOPE_AGENT);
}
__device__ inline uint4 ld_b128_sc(const unsigned short* p){
  uint4 r;
  asm volatile("global_load_dwordx4 %0, %1, off sc0 sc1"
               : "=&v"(r) : "v"(p) : "memory");
  return r;
}
__device__ inline unsigned int poll_flag(const unsigned int* p){
  unsigned int r;
  asm volatile("global_load_dword %0, %1, off sc0 sc1\n\ts_waitcnt vmcnt(0)"
               : "=&v"(r) : "v"(p) : "memory");
  return r;
}
__device__ inline void wait_vm0(){ asm volatile("s_waitcnt vmcnt(0)" ::: "memory"); }

__global__ __launch_bounds__(256)
void split_fp32(const float* __restrict__ x,
                unsigned short* __restrict__ hi,
                unsigned short* __restrict__ lo, int n4){
  int i = blockIdx.x * 256 + threadIdx.x;
  if (i >= n4) return;
  float4 v = ((const float4*)x)[i];
  ushort4 h, l;
  h.x = f2bf(v.x); l.x = f2bf(v.x - bf2f(h.x));
  h.y = f2bf(v.y); l.y = f2bf(v.y - bf2f(h.y));
  h.z = f2bf(v.z); l.z = f2bf(v.z - bf2f(h.z));
  h.w = f2bf(v.w); l.w = f2bf(v.w - bf2f(h.w));
  ((ushort4*)hi)[i] = h;
  ((ushort4*)lo)[i] = l;
}

// h0 = p0(64x512) @ Winit(4096x512)^T, 3-term. Writes h in SWIZZLED global layout.
__global__ __launch_bounds__(512, 2)
void h0_mm(const float* __restrict__ p0,
           const float* __restrict__ Wini,
           unsigned short* __restrict__ oHi,
           unsigned short* __restrict__ oLo)
{
  const int nb = blockIdx.x;
  const int tid = threadIdx.x, lane = tid & 63, wave = tid >> 6;
  const int quad = lane >> 4, l16 = lane & 15;
  const int mw = wave & 3, nw = wave >> 2;
  __shared__ __attribute__((aligned(16))) unsigned short BH[128*40];
  __shared__ __attribute__((aligned(16))) unsigned short BL[128*40];
  const int srow = tid >> 2, sk = (tid & 3) << 3;
  const float* wp = Wini + (size_t)(nb*128 + srow)*512 + sk;
  const float* ap = p0 + (size_t)(mw*16 + l16)*512 + quad*8;
  f32x4 acc[4];
  #pragma unroll
  for (int tn = 0; tn < 4; ++tn) acc[tn] = (f32x4){0.f,0.f,0.f,0.f};
  for (int kc = 0; kc < 16; ++kc){
    float4 f0 = *(const float4*)(wp + kc*32);
    float4 f1 = *(const float4*)(wp + kc*32 + 4);
    uint4 hi, lo; split8(f0, f1, hi, lo);
    __syncthreads();
    *(uint4*)&BH[srow*40 + sk] = hi;
    *(uint4*)&BL[srow*40 + sk] = lo;
    __syncthreads();
    float4 a0 = *(const float4*)(ap + kc*32);
    float4 a1 = *(const float4*)(ap + kc*32 + 4);
    uint4 ahi, alo; split8(a0, a1, ahi, alo);
    U16x8 aU, lU; aU.u4 = ahi; lU.u4 = alo;
    #pragma unroll
    for (int tn = 0; tn < 4; ++tn){
      U16x8 bh, bl;
      const int off = (nw*64 + tn*16 + l16)*40 + quad*8;
      bh.u4 = *(const uint4*)&BH[off];
      bl.u4 = *(const uint4*)&BL[off];
      acc[tn] = MFMA16(aU, bh, acc[tn]);
      acc[tn] = MFMA16(aU, bl, acc[tn]);
      acc[tn] = MFMA16(lU, bh, acc[tn]);
    }
  }
  #pragma unroll
  for (int tn = 0; tn < 4; ++tn){
    const int n = nb*128 + nw*64 + tn*16 + l16;
    #pragma unroll
    for (int r = 0; r < 4; ++r){
      const int row = mw*16 + quad*4 + r;
      const int g = n >> 3, gp = (g & ~7) | ((g & 7) ^ (row & 7));
      const int np = (gp << 3) | (n & 7);
      float val = acc[tn][r];
      unsigned short hh = f2bf(val);
      oHi[(size_t)row*4096 + np] = hh;
      oLo[(size_t)row*4096 + np] = f2bf(val - bf2f(hh));
    }
  }
}

// Persistent RNN: 256 blocks (kb=bx&7, nb=bx>>3) x 512 thr. W hi/lo in VGPRs.
// r5 delta vs r0 (verified 3618us): both tree barriers replaced by single-writer
// monotone flags + dependency-exact 64-lane parallel polls; part double-buffered
// (WAR closed by the flag-graph 2-step skew bound). All data semantics = r0 (sc1).
// Flags (dwords, 16B stride): partDone[bx] at bar[bx*4]  (tile bx partials ready,
// value s+1); prodDone[bx] at bar[1024 + bx*4] (block bx's h slice written, s+1).
//   stage(kb) of step s needs h rows r written by blocks 4r+(kb>>1): poll >= s.
//   reduce of block bx needs tiles (bx&3)*64+j, j=0..63: poll partDone >= s+1.
__global__ __launch_bounds__(512, 2)
void rnn_persist(const float* __restrict__ W,
                 const float* __restrict__ v,
                 const float* __restrict__ Wih,
                 unsigned short* __restrict__ hHiA,
                 unsigned short* __restrict__ hLoA,
                 unsigned short* __restrict__ hHiB,
                 unsigned short* __restrict__ hLoB,
                 float* __restrict__ part,
                 unsigned int* __restrict__ bar,
                 unsigned short* __restrict__ G)
{
  const int bx = blockIdx.x, kb = bx & 7, nb = bx >> 3;
  const int tid = threadIdx.x, lane = tid & 63, wave = tid >> 6;
  const int quad = lane >> 4, l16 = lane & 15;
  __shared__ __attribute__((aligned(16))) unsigned short AH[64*512];  // 64 KB
  __shared__ __attribute__((aligned(16))) unsigned short AL[64*512];  // 64 KB

  unsigned int* partDone = bar;          // [256], stride 4 dwords
  unsigned int* prodDone = bar + 1024;   // [256], stride 4 dwords

  // W slice -> registers: wave owns 16 cols (nb*128 + wave*16 + l16), k-slice kb*512
  uint4 whi[16], wlo[16];
  {
    const float* wp = W + (size_t)(nb*128 + wave*16 + l16)*4096 + kb*512 + quad*8;
    #pragma unroll
    for (int c = 0; c < 16; ++c){
      float4 f0 = *(const float4*)(wp + c*32);
      float4 f1 = *(const float4*)(wp + c*32 + 4);
      split8(f0, f1, whi[c], wlo[c]);
    }
  }

  const int redM = bx >> 2;
  const int nbase = ((bx & 3) << 10) + (tid << 1);
  const int cR = kb >> 1;                 // col-class of this block's stage slice

  for (int s = 0; s < 128; ++s){
    const unsigned short* hH = (s & 1) ? hHiB : hHiA;
    const unsigned short* hL = (s & 1) ? hLoB : hLoA;
    unsigned short* nHi = (s & 1) ? hHiA : hHiB;
    unsigned short* nLo = (s & 1) ? hLoA : hLoB;
    float* pbuf = part + (size_t)(s & 1) * 2097152;   // [256][8192] f32

    // ---- wait: exact producers of h(s) k-slice kb (skip s=0: h0_mm) ----
    if (s > 0){
      if (tid < 64){
        const unsigned int* f = prodDone + (tid*4 + cR)*4;
        while ((int)poll_flag(f) < s) __builtin_amdgcn_s_sleep(2);
      }
      __syncthreads();
    }

    // ---- stage h k-slice (swizzled-global verbatim copy) via sc1 b128 loads ----
    {
      uint4 stg[16];
      #pragma unroll
      for (int i = 0; i < 8; ++i){
        const int flat = tid + i*512, row = flat >> 6, g = flat & 63;
        stg[i] = ld_b128_sc(hH + (size_t)row*4096 + (kb << 9) + g*8);
      }
      #pragma unroll
      for (int i = 0; i < 8; ++i){
        const int flat = tid + i*512, row = flat >> 6, g = flat & 63;
        stg[8 + i] = ld_b128_sc(hL + (size_t)row*4096 + (kb << 9) + g*8);
      }
      asm volatile("s_waitcnt vmcnt(8)" ::: "memory");
      #pragma unroll
      for (int i = 0; i < 8; ++i){
        const int flat = tid + i*512, row = flat >> 6, g = flat & 63;
        *(uint4*)&AH[row*512 + g*8] = stg[i];
      }
      asm volatile("s_waitcnt vmcnt(0)" ::: "memory");
      #pragma unroll
      for (int i = 0; i < 8; ++i){
        const int flat = tid + i*512, row = flat >> 6, g = flat & 63;
        *(uint4*)&AL[row*512 + g*8] = stg[8 + i];
      }
    }
    __syncthreads();

    // ---- MFMA: 16 k-chunks x 4 m-tiles x 3 terms (3 independent chains) ----
    f32x4 a0[4], a1[4], a2[4];
    #pragma unroll
    for (int mt = 0; mt < 4; ++mt){
      a0[mt] = (f32x4){0.f,0.f,0.f,0.f};
      a1[mt] = (f32x4){0.f,0.f,0.f,0.f};
      a2[mt] = (f32x4){0.f,0.f,0.f,0.f};
    }
    #pragma unroll
    for (int c = 0; c < 16; ++c){
      U16x8 bh, bl; bh.u4 = whi[c]; bl.u4 = wlo[c];
      #pragma unroll
      for (int mt = 0; mt < 4; ++mt){
        const int row = mt*16 + l16;
        const int gk = c*4 + quad;
        const int phys = (gk & 56) | ((gk & 7) ^ (row & 7));
        U16x8 ah, al;
        ah.u4 = *(const uint4*)&AH[row*512 + phys*8];
        al.u4 = *(const uint4*)&AL[row*512 + phys*8];
        a0[mt] = MFMA16(ah, bh, a0[mt]);
        a1[mt] = MFMA16(ah, bl, a1[mt]);
        a2[mt] = MFMA16(al, bh, a2[mt]);
      }
    }

    // ---- partial store (sc1 write-through): tile layout [buf][bx][w][m][c16] ----
    {
      float* pb = pbuf + (size_t)bx*8192 + wave*1024 + l16;
      #pragma unroll
      for (int mt = 0; mt < 4; ++mt)
        #pragma unroll
        for (int r = 0; r < 4; ++r)
          st_f32_sc(pb + (mt*16 + quad*4 + r)*16, a0[mt][r] + a1[mt][r] + a2[mt][r]);
    }
    wait_vm0();
    __syncthreads();
    if (tid == 0) st_u32_sc(&partDone[bx*4], (unsigned)(s + 1));

    // ---- wait: exact 64 partial tiles this block reduces ----
    if (tid < 64){
      const unsigned int* f = partDone + ((bx & 3)*64 + tid)*4;
      while ((int)poll_flag(f) < s + 1) __builtin_amdgcn_s_sleep(2);
    }
    __syncthreads();

    // ---- distributed reduce: 2 elems/thread (row redM, cols nbase, nbase+1) ----
    {
      float2 sum = {0.f, 0.f};
      const size_t off = (size_t)((nbase >> 4) & 7)*1024 + redM*16 + (nbase & 15);
      #pragma unroll
      for (int k2 = 0; k2 < 8; ++k2){
        unsigned long long q = ld_u64_sc((const unsigned long long*)
            (pbuf + (size_t)((nbase >> 7)*8 + k2)*8192 + off));
        float2 p; __builtin_memcpy(&p, &q, 8);
        sum.x += p.x; sum.y += p.y;
      }
      const float2 vv = *(const float2*)(v + ((size_t)redM*128 + s)*2);
      const float4 wi = *(const float4*)(Wih + (size_t)nbase*2);
      float v0 = fmaxf(sum.x + vv.x*wi.x + vv.y*wi.y, 0.f);
      float v1 = fmaxf(sum.y + vv.x*wi.z + vv.y*wi.w, 0.f);
      const unsigned short h0 = f2bf(v0), h1 = f2bf(v1);
      const unsigned short q0 = f2bf(v0 - bf2f(h0)), q1 = f2bf(v1 - bf2f(h1));
      const int g = nbase >> 3, gp = (g & ~7) | ((g & 7) ^ (redM & 7));
      const int np = (gp << 3) | (nbase & 7);
      st_u32_sc((unsigned int*)(nHi + (size_t)redM*4096 + np),
                (unsigned)h0 | ((unsigned)h1 << 16));
      st_u32_sc((unsigned int*)(nLo + (size_t)redM*4096 + np),
                (unsigned)q0 | ((unsigned)q1 << 16));
      __builtin_nontemporal_store((unsigned)h0 | ((unsigned)h1 << 16),
          (unsigned int*)(G + (size_t)s*262144 + (size_t)redM*4096 + nbase));
    }
    wait_vm0();
    __syncthreads();
    if (tid == 0) st_u32_sc(&prodDone[bx*4], (unsigned)(s + 1));
  }
}

// out = G(8192 x 4096, hi-only) @ Wdec(512x4096)^T, 2-term (pre-split bf16).
__global__ __launch_bounds__(256, 1)
void decode_g(const unsigned short* __restrict__ G,
              const unsigned short* __restrict__ WdH,
              const unsigned short* __restrict__ WdL,
              float* __restrict__ out)
{
  const int tid = threadIdx.x, lane = tid & 63, wave = tid >> 6;
  const int quad = lane >> 4, l16 = lane & 15;
  const int wm = wave & 1, wn = wave >> 1;
  const int m0 = blockIdx.x * 128;
  const int n0 = blockIdx.y * 128;
  __shared__ __attribute__((aligned(16))) unsigned short BH[2][128*64];
  __shared__ __attribute__((aligned(16))) unsigned short BL[2][128*64];

  const unsigned short* gp[4];
  #pragma unroll
  for (int tm = 0; tm < 4; ++tm)
    gp[tm] = G + (size_t)(m0 + wm*64 + tm*16 + l16)*4096 + quad*8;

  #define LD_B(c, h4, l4) { _Pragma("unroll") \
    for (int i = 0; i < 4; ++i){ const int q = tid + i*256, row = q >> 3, gk = q & 7; \
      const size_t so = (size_t)(n0 + row)*4096 + (size_t)(c)*64 + gk*8; \
      (h4)[i] = *(const uint4*)(WdH + so); (l4)[i] = *(const uint4*)(WdL + so); } }
  #define ST_B(buf, h4, l4) { _Pragma("unroll") \
    for (int i = 0; i < 4; ++i){ const int q = tid + i*256, row = q >> 3, gk = q & 7; \
      const int phys = gk ^ (row & 7); \
      *(uint4*)&BH[buf][row*64 + phys*8] = (h4)[i]; \
      *(uint4*)&BL[buf][row*64 + phys*8] = (l4)[i]; } }
  #define LD_A(c, dst) { _Pragma("unroll") \
    for (int tm = 0; tm < 4; ++tm){ _Pragma("unroll") \
      for (int ks = 0; ks < 2; ++ks) \
        (dst)[tm][ks] = *(const uint4*)(gp[tm] + (size_t)(c)*64 + ks*32); } }

  f32x4 acc[4][4];
  #pragma unroll
  for (int a = 0; a < 4; ++a)
    #pragma unroll
    for (int b = 0; b < 4; ++b) acc[a][b] = (f32x4){0.f,0.f,0.f,0.f};

  uint4 pbh[4], pbl[4];
  uint4 ar[2][4][2];
  LD_B(0, pbh, pbl); ST_B(0, pbh, pbl);
  LD_A(0, ar[0]);
  LD_A(1, ar[1]);
  LD_B(1, pbh, pbl);
  __syncthreads();

  for (int c = 0; c < 64; ++c){
    const int cur = c & 1;
    #pragma unroll
    for (int ks = 0; ks < 2; ++ks){
      U16x8 bh[4], bl[4];
      #pragma unroll
      for (int tn = 0; tn < 4; ++tn){
        const int row = wn*64 + tn*16 + l16;
        const int gk = ks*4 + quad;
        const int phys = gk ^ (row & 7);
        bh[tn].u4 = *(const uint4*)&BH[cur][row*64 + phys*8];
        bl[tn].u4 = *(const uint4*)&BL[cur][row*64 + phys*8];
      }
      #pragma unroll
      for (int tm = 0; tm < 4; ++tm){
        U16x8 a; a.u4 = ar[cur][tm][ks];
        #pragma unroll
        for (int tn = 0; tn < 4; ++tn){
          acc[tm][tn] = MFMA16(a, bh[tn], acc[tm][tn]);
          acc[tm][tn] = MFMA16(a, bl[tn], acc[tm][tn]);
        }
      }
    }
    if (c + 2 < 64) LD_A(c+2, ar[cur]);
    if (c + 1 < 64){
      ST_B(cur ^ 1, pbh, pbl);
      if (c + 2 < 64) LD_B(c+2, pbh, pbl);
      __syncthreads();
    }
  }
  #pragma unroll
  for (int tm = 0; tm < 4; ++tm){
    #pragma unroll
    for (int tn = 0; tn < 4; ++tn){
      const int p = n0 + wn*64 + tn*16 + l16;
      #pragma unroll
      for (int r = 0; r < 4; ++r){
        const int rm = m0 + wm*64 + tm*16 + quad*4 + r;
        out[((size_t)(rm & 63)*128 + (rm >> 6))*512 + p] = acc[tm][tn][r];
      }
    }
  }
}

extern "C" void kernel_launch(void* const* d_in, const int* in_sizes, int n_in,
                              void* d_out, int out_size, void* d_ws, size_t ws_size,
                              hipStream_t stream) {
  const float* v    = (const float*)d_in[0];
  const float* p0   = (const float*)d_in[1];
  const float* Wini = (const float*)d_in[2];
  const float* Wih  = (const float*)d_in[3];
  const float* Whh  = (const float*)d_in[4];
  const float* Wdec = (const float*)d_in[5];
  float* out = (float*)d_out;
  char* wsb = (char*)d_ws;

  // ws layout (bytes)
  unsigned int*   bar  = (unsigned int*)(wsb + 0);          // 16 KB (flags)
  unsigned short* hHiA = (unsigned short*)(wsb + 16384);
  unsigned short* hLoA = (unsigned short*)(wsb + 540672);
  unsigned short* hHiB = (unsigned short*)(wsb + 1064960);
  unsigned short* hLoB = (unsigned short*)(wsb + 1589248);
  float*          part = (float*)(wsb + 2113536);           // 16 MB = [2][256][8192] f32
  unsigned short* WdH  = (unsigned short*)(wsb + 18890752); // 4 MB
  unsigned short* WdL  = (unsigned short*)(wsb + 23085056); // 4 MB
  unsigned short* G    = (unsigned short*)(wsb + 27279360); // 64 MB
  // end ~94.4 MB

  hipMemsetAsync(bar, 0, 16384, stream);
  split_fp32<<<dim3(2048), dim3(256), 0, stream>>>(Wdec, WdH, WdL, 524288);
  h0_mm<<<dim3(32), dim3(512), 0, stream>>>(p0, Wini, hHiA, hLoA);
  rnn_persist<<<dim3(256), dim3(512), 0, stream>>>(Whh, v, Wih,
                                                   hHiA, hLoA, hHiB, hLoB,
                                                   part, bar, G);
  decode_g<<<dim3(64, 4), dim3(256), 0, stream>>>(G, WdH, WdL, out);
}

// Round 6
// 2596.968 us; speedup vs baseline: 2.0158x; 1.0289x over previous
//
#include <hip/hip_runtime.h>

typedef __attribute__((ext_vector_type(8))) short short8;
typedef __attribute__((ext_vector_type(4))) float f32x4;
union U16x8 { uint4 u4; short8 s8; };

__device__ inline float bf2f(unsigned short u){
  unsigned int x = ((unsigned int)u) << 16;
  float f; __builtin_memcpy(&f, &x, 4); return f;
}
__device__ inline unsigned short f2bf(float f){
  unsigned int x; __builtin_memcpy(&x, &f, 4);
  x = x + 0x7FFFu + ((x >> 16) & 1u);
  return (unsigned short)(x >> 16);
}
__device__ inline void split4(float4 f, uint2& hi, uint2& lo){
  unsigned short h0=f2bf(f.x), h1=f2bf(f.y), h2=f2bf(f.z), h3=f2bf(f.w);
  unsigned short l0=f2bf(f.x-bf2f(h0)), l1=f2bf(f.y-bf2f(h1)),
                 l2=f2bf(f.z-bf2f(h2)), l3=f2bf(f.w-bf2f(h3));
  hi = (uint2){(unsigned)h0 | ((unsigned)h1<<16), (unsigned)h2 | ((unsigned)h3<<16)};
  lo = (uint2){(unsigned)l0 | ((unsigned)l1<<16), (unsigned)l2 | ((unsigned)l3<<16)};
}
__device__ inline void split8(float4 f0, float4 f1, uint4& hi, uint4& lo){
  uint2 h0,l0,h1,l1; split4(f0,h0,l0); split4(f1,h1,l1);
  hi = (uint4){h0.x,h0.y,h1.x,h1.y};
  lo = (uint4){l0.x,l0.y,l1.x,l1.y};
}

#define MFMA16(a,b,c) __builtin_amdgcn_mfma_f32_16x16x32_bf16((a).s8,(b).s8,(c),0,0,0)

// device-scope (sc1) fine-grained ops — cross-XCD coherent without cache flushes
__device__ inline void st_f32_sc(float* p, float v){
  __hip_atomic_store(p, v, __ATOMIC_RELAXED, __HIP_MEMORY_SCOPE_AGENT);
}
__device__ inline void st_u32_sc(unsigned int* p, unsigned int v){
  __hip_atomic_store(p, v, __ATOMIC_RELAXED, __HIP_MEMORY_SCOPE_AGENT);
}
__device__ inline unsigned long long ld_u64_sc(const unsigned long long* p){
  return __hip_atomic_load(p, __ATOMIC_RELAXED, __HIP_MEMORY_SCOPE_AGENT);
}
__device__ inline uint4 ld_b128_sc(const unsigned short* p){
  uint4 r;
  asm volatile("global_load_dwordx4 %0, %1, off sc0 sc1"
               : "=&v"(r) : "v"(p) : "memory");
  return r;
}
__device__ inline unsigned int poll_flag(const unsigned int* p){
  unsigned int r;
  asm volatile("global_load_dword %0, %1, off sc0 sc1\n\ts_waitcnt vmcnt(0)"
               : "=&v"(r) : "v"(p) : "memory");
  return r;
}
__device__ inline void wait_vm0(){ asm volatile("s_waitcnt vmcnt(0)" ::: "memory"); }

__global__ __launch_bounds__(256)
void split_fp32(const float* __restrict__ x,
                unsigned short* __restrict__ hi,
                unsigned short* __restrict__ lo, int n4){
  int i = blockIdx.x * 256 + threadIdx.x;
  if (i >= n4) return;
  float4 v = ((const float4*)x)[i];
  ushort4 h, l;
  h.x = f2bf(v.x); l.x = f2bf(v.x - bf2f(h.x));
  h.y = f2bf(v.y); l.y = f2bf(v.y - bf2f(h.y));
  h.z = f2bf(v.z); l.z = f2bf(v.z - bf2f(h.z));
  h.w = f2bf(v.w); l.w = f2bf(v.w - bf2f(h.w));
  ((ushort4*)hi)[i] = h;
  ((ushort4*)lo)[i] = l;
}

// h0 = p0(64x512) @ Winit(4096x512)^T, 3-term. Writes h in SWIZZLED global layout.
__global__ __launch_bounds__(512, 2)
void h0_mm(const float* __restrict__ p0,
           const float* __restrict__ Wini,
           unsigned short* __restrict__ oHi,
           unsigned short* __restrict__ oLo)
{
  const int nb = blockIdx.x;
  const int tid = threadIdx.x, lane = tid & 63, wave = tid >> 6;
  const int quad = lane >> 4, l16 = lane & 15;
  const int mw = wave & 3, nw = wave >> 2;
  __shared__ __attribute__((aligned(16))) unsigned short BH[128*40];
  __shared__ __attribute__((aligned(16))) unsigned short BL[128*40];
  const int srow = tid >> 2, sk = (tid & 3) << 3;
  const float* wp = Wini + (size_t)(nb*128 + srow)*512 + sk;
  const float* ap = p0 + (size_t)(mw*16 + l16)*512 + quad*8;
  f32x4 acc[4];
  #pragma unroll
  for (int tn = 0; tn < 4; ++tn) acc[tn] = (f32x4){0.f,0.f,0.f,0.f};
  for (int kc = 0; kc < 16; ++kc){
    float4 f0 = *(const float4*)(wp + kc*32);
    float4 f1 = *(const float4*)(wp + kc*32 + 4);
    uint4 hi, lo; split8(f0, f1, hi, lo);
    __syncthreads();
    *(uint4*)&BH[srow*40 + sk] = hi;
    *(uint4*)&BL[srow*40 + sk] = lo;
    __syncthreads();
    float4 a0 = *(const float4*)(ap + kc*32);
    float4 a1 = *(const float4*)(ap + kc*32 + 4);
    uint4 ahi, alo; split8(a0, a1, ahi, alo);
    U16x8 aU, lU; aU.u4 = ahi; lU.u4 = alo;
    #pragma unroll
    for (int tn = 0; tn < 4; ++tn){
      U16x8 bh, bl;
      const int off = (nw*64 + tn*16 + l16)*40 + quad*8;
      bh.u4 = *(const uint4*)&BH[off];
      bl.u4 = *(const uint4*)&BL[off];
      acc[tn] = MFMA16(aU, bh, acc[tn]);
      acc[tn] = MFMA16(aU, bl, acc[tn]);
      acc[tn] = MFMA16(lU, bh, acc[tn]);
    }
  }
  #pragma unroll
  for (int tn = 0; tn < 4; ++tn){
    const int n = nb*128 + nw*64 + tn*16 + l16;
    #pragma unroll
    for (int r = 0; r < 4; ++r){
      const int row = mw*16 + quad*4 + r;
      const int g = n >> 3, gp = (g & ~7) | ((g & 7) ^ (row & 7));
      const int np = (gp << 3) | (n & 7);
      float val = acc[tn][r];
      unsigned short hh = f2bf(val);
      oHi[(size_t)row*4096 + np] = hh;
      oLo[(size_t)row*4096 + np] = f2bf(val - bf2f(hh));
    }
  }
}

// Persistent RNN: 256 blocks (kb=bx&7, nb=bx>>3) x 512 thr. W hi/lo in VGPRs.
// r6 delta vs r5 (verified 2672us): batch rows split into two independent
// 32-row groups (A=0..31, B=32..63), software-pipelined within each block:
//   stageA -> LDS -> issue B stage loads (fly under mfmaA) -> mfmaA ->
//   storeA -> vmcnt0 (drains B loads + A stores together) -> pA ->
//   LDS B -> mfmaB -> storeB -> pB -> reduce own group (A if bx<128 else B).
// Hides B's stage drain + pA detection skew; both h-recurrence hops gain slack
// (h_A ready ~75% through step, used at next start; h_B at 100%, used ~40% in).
// Flag fabric identical in shape to r5: monotone single-writer flags,
// dependency-exact 64-lane polls. Partial tile layout unchanged (A-half rows
// 0..31, B-half rows 32..63 of the same [bx][w][row][l16] tile) -> reduce code
// identical. Part double-buffered; WAR closed by the same 2-step skew bound.
// Flags (16B stride): pA[bx]=bar[bx*4], pB[bx]=bar[1024+bx*4],
// prodDone[bx]=bar[2048+bx*4].
__global__ __launch_bounds__(512, 2)
void rnn_persist(const float* __restrict__ W,
                 const float* __restrict__ v,
                 const float* __restrict__ Wih,
                 unsigned short* __restrict__ hHiA,
                 unsigned short* __restrict__ hLoA,
                 unsigned short* __restrict__ hHiB,
                 unsigned short* __restrict__ hLoB,
                 float* __restrict__ part,
                 unsigned int* __restrict__ bar,
                 unsigned short* __restrict__ G)
{
  const int bx = blockIdx.x, kb = bx & 7, nb = bx >> 3;
  const int tid = threadIdx.x, lane = tid & 63, wave = tid >> 6;
  const int quad = lane >> 4, l16 = lane & 15;
  __shared__ __attribute__((aligned(16))) unsigned short AH[32*512];  // 32 KB
  __shared__ __attribute__((aligned(16))) unsigned short AL[32*512];  // 32 KB

  unsigned int* pA       = bar;          // [256], stride 4 dwords
  unsigned int* pB       = bar + 1024;   // [256], stride 4 dwords
  unsigned int* prodDone = bar + 2048;   // [256], stride 4 dwords

  // W slice -> registers: wave owns 16 cols (nb*128 + wave*16 + l16), k-slice kb*512
  uint4 whi[16], wlo[16];
  {
    const float* wp = W + (size_t)(nb*128 + wave*16 + l16)*4096 + kb*512 + quad*8;
    #pragma unroll
    for (int c = 0; c < 16; ++c){
      float4 f0 = *(const float4*)(wp + c*32);
      float4 f1 = *(const float4*)(wp + c*32 + 4);
      split8(f0, f1, whi[c], wlo[c]);
    }
  }

  const int redM = bx >> 2;                 // row this block reduces (0..63)
  const int nbase = ((bx & 3) << 10) + (tid << 1);
  const int cR = kb >> 1;                   // col-quarter class of stage slice
  const bool aRed = (bx < 128);             // redM < 32  <=>  group-A reducer

  for (int s = 0; s < 128; ++s){
    const unsigned short* hH = (s & 1) ? hHiB : hHiA;
    const unsigned short* hL = (s & 1) ? hLoB : hLoA;
    unsigned short* nHi = (s & 1) ? hHiA : hHiB;
    unsigned short* nLo = (s & 1) ? hLoA : hLoB;
    float* pbuf = part + (size_t)(s & 1) * 2097152;   // [256][8192] f32

    // ---- wait: exact producers of h(s) k-slice kb, both groups ----
    // lane t<32 polls A-row producers (bx'=4t+cR < 128), t in 32..63 polls B.
    if (s > 0){
      if (tid < 64){
        const unsigned int* f = prodDone + (tid*4 + cR)*4;
        while ((int)poll_flag(f) < s) __builtin_amdgcn_s_sleep(1);
      }
      __syncthreads();
    }

    // ---- stage group A (rows 0..31), k-slice kb ----
    {
      uint4 stg[8];
      #pragma unroll
      for (int i = 0; i < 4; ++i){
        const int flat = tid + i*512, row = flat >> 6, g = flat & 63;
        stg[i]     = ld_b128_sc(hH + (size_t)row*4096 + (kb << 9) + g*8);
        stg[4 + i] = ld_b128_sc(hL + (size_t)row*4096 + (kb << 9) + g*8);
      }
      wait_vm0();
      #pragma unroll
      for (int i = 0; i < 4; ++i){
        const int flat = tid + i*512, row = flat >> 6, g = flat & 63;
        *(uint4*)&AH[row*512 + g*8] = stg[i];
        *(uint4*)&AL[row*512 + g*8] = stg[4 + i];
      }
    }
    __syncthreads();

    // ---- issue group-B stage loads (rows 32..63); fly under mfmaA ----
    uint4 stgB[8];
    #pragma unroll
    for (int i = 0; i < 4; ++i){
      const int flat = tid + i*512, row = 32 + (flat >> 6), g = flat & 63;
      stgB[i]     = ld_b128_sc(hH + (size_t)row*4096 + (kb << 9) + g*8);
      stgB[4 + i] = ld_b128_sc(hL + (size_t)row*4096 + (kb << 9) + g*8);
    }

    // ---- mfma A: 16 k-chunks x 2 m-tiles x 3 terms ----
    {
      f32x4 a0[2], a1[2], a2[2];
      #pragma unroll
      for (int mt = 0; mt < 2; ++mt){
        a0[mt] = (f32x4){0.f,0.f,0.f,0.f};
        a1[mt] = (f32x4){0.f,0.f,0.f,0.f};
        a2[mt] = (f32x4){0.f,0.f,0.f,0.f};
      }
      #pragma unroll
      for (int c = 0; c < 16; ++c){
        U16x8 bh, bl; bh.u4 = whi[c]; bl.u4 = wlo[c];
        #pragma unroll
        for (int mt = 0; mt < 2; ++mt){
          const int row = mt*16 + l16;
          const int gk = c*4 + quad;
          const int phys = (gk & 56) | ((gk & 7) ^ (row & 7));
          U16x8 ah, al;
          ah.u4 = *(const uint4*)&AH[row*512 + phys*8];
          al.u4 = *(const uint4*)&AL[row*512 + phys*8];
          a0[mt] = MFMA16(ah, bh, a0[mt]);
          a1[mt] = MFMA16(ah, bl, a1[mt]);
          a2[mt] = MFMA16(al, bh, a2[mt]);
        }
      }
      // ---- store A partials (rows 0..31 of tile) ----
      float* pb = pbuf + (size_t)bx*8192 + wave*1024 + l16;
      #pragma unroll
      for (int mt = 0; mt < 2; ++mt)
        #pragma unroll
        for (int r = 0; r < 4; ++r)
          st_f32_sc(pb + (mt*16 + quad*4 + r)*16, a0[mt][r] + a1[mt][r] + a2[mt][r]);
    }
    wait_vm0();          // drains B stage loads AND A partial stores
    __syncthreads();     // all waves: stores retired, mfmaA LDS reads done
    if (tid == 0) st_u32_sc(&pA[bx*4], (unsigned)(s + 1));

    // ---- LDS B (reuse AH/AL) ----
    #pragma unroll
    for (int i = 0; i < 4; ++i){
      const int flat = tid + i*512, row = flat >> 6, g = flat & 63;
      *(uint4*)&AH[row*512 + g*8] = stgB[i];
      *(uint4*)&AL[row*512 + g*8] = stgB[4 + i];
    }
    __syncthreads();

    // ---- mfma B ----
    {
      f32x4 a0[2], a1[2], a2[2];
      #pragma unroll
      for (int mt = 0; mt < 2; ++mt){
        a0[mt] = (f32x4){0.f,0.f,0.f,0.f};
        a1[mt] = (f32x4){0.f,0.f,0.f,0.f};
        a2[mt] = (f32x4){0.f,0.f,0.f,0.f};
      }
      #pragma unroll
      for (int c = 0; c < 16; ++c){
        U16x8 bh, bl; bh.u4 = whi[c]; bl.u4 = wlo[c];
        #pragma unroll
        for (int mt = 0; mt < 2; ++mt){
          const int row = mt*16 + l16;            // local row; row&7 == global&7
          const int gk = c*4 + quad;
          const int phys = (gk & 56) | ((gk & 7) ^ (row & 7));
          U16x8 ah, al;
          ah.u4 = *(const uint4*)&AH[row*512 + phys*8];
          al.u4 = *(const uint4*)&AL[row*512 + phys*8];
          a0[mt] = MFMA16(ah, bh, a0[mt]);
          a1[mt] = MFMA16(ah, bl, a1[mt]);
          a2[mt] = MFMA16(al, bh, a2[mt]);
        }
      }
      // ---- store B partials (rows 32..63 of tile) ----
      float* pb = pbuf + (size_t)bx*8192 + wave*1024 + l16;
      #pragma unroll
      for (int mt = 0; mt < 2; ++mt)
        #pragma unroll
        for (int r = 0; r < 4; ++r)
          st_f32_sc(pb + (32 + mt*16 + quad*4 + r)*16, a0[mt][r] + a1[mt][r] + a2[mt][r]);
    }
    wait_vm0();
    __syncthreads();
    if (tid == 0) st_u32_sc(&pB[bx*4], (unsigned)(s + 1));

    // ---- wait: exact 64 partial tiles of OWN group, then reduce ----
    if (tid < 64){
      const unsigned int* f = (aRed ? pA : pB) + ((bx & 3)*64 + tid)*4;
      while ((int)poll_flag(f) < s + 1) __builtin_amdgcn_s_sleep(1);
    }
    __syncthreads();

    // ---- distributed reduce: 2 elems/thread (row redM, cols nbase, nbase+1) ----
    {
      float2 sum = {0.f, 0.f};
      const size_t off = (size_t)((nbase >> 4) & 7)*1024 + redM*16 + (nbase & 15);
      #pragma unroll
      for (int k2 = 0; k2 < 8; ++k2){
        unsigned long long q = ld_u64_sc((const unsigned long long*)
            (pbuf + (size_t)((nbase >> 7)*8 + k2)*8192 + off));
        float2 p; __builtin_memcpy(&p, &q, 8);
        sum.x += p.x; sum.y += p.y;
      }
      const float2 vv = *(const float2*)(v + ((size_t)redM*128 + s)*2);
      const float4 wi = *(const float4*)(Wih + (size_t)nbase*2);
      float v0 = fmaxf(sum.x + vv.x*wi.x + vv.y*wi.y, 0.f);
      float v1 = fmaxf(sum.y + vv.x*wi.z + vv.y*wi.w, 0.f);
      const unsigned short h0 = f2bf(v0), h1 = f2bf(v1);
      const unsigned short q0 = f2bf(v0 - bf2f(h0)), q1 = f2bf(v1 - bf2f(h1));
      const int g = nbase >> 3, gp = (g & ~7) | ((g & 7) ^ (redM & 7));
      const int np = (gp << 3) | (nbase & 7);
      st_u32_sc((unsigned int*)(nHi + (size_t)redM*4096 + np),
                (unsigned)h0 | ((unsigned)h1 << 16));
      st_u32_sc((unsigned int*)(nLo + (size_t)redM*4096 + np),
                (unsigned)q0 | ((unsigned)q1 << 16));
      __builtin_nontemporal_store((unsigned)h0 | ((unsigned)h1 << 16),
          (unsigned int*)(G + (size_t)s*262144 + (size_t)redM*4096 + nbase));
    }
    wait_vm0();
    __syncthreads();
    if (tid == 0) st_u32_sc(&prodDone[bx*4], (unsigned)(s + 1));
  }
}

// out = G(8192 x 4096, hi-only) @ Wdec(512x4096)^T, 2-term (pre-split bf16).
__global__ __launch_bounds__(256, 1)
void decode_g(const unsigned short* __restrict__ G,
              const unsigned short* __restrict__ WdH,
              const unsigned short* __restrict__ WdL,
              float* __restrict__ out)
{
  const int tid = threadIdx.x, lane = tid & 63, wave = tid >> 6;
  const int quad = lane >> 4, l16 = lane & 15;
  const int wm = wave & 1, wn = wave >> 1;
  const int m0 = blockIdx.x * 128;
  const int n0 = blockIdx.y * 128;
  __shared__ __attribute__((aligned(16))) unsigned short BH[2][128*64];
  __shared__ __attribute__((aligned(16))) unsigned short BL[2][128*64];

  const unsigned short* gp[4];
  #pragma unroll
  for (int tm = 0; tm < 4; ++tm)
    gp[tm] = G + (size_t)(m0 + wm*64 + tm*16 + l16)*4096 + quad*8;

  #define LD_B(c, h4, l4) { _Pragma("unroll") \
    for (int i = 0; i < 4; ++i){ const int q = tid + i*256, row = q >> 3, gk = q & 7; \
      const size_t so = (size_t)(n0 + row)*4096 + (size_t)(c)*64 + gk*8; \
      (h4)[i] = *(const uint4*)(WdH + so); (l4)[i] = *(const uint4*)(WdL + so); } }
  #define ST_B(buf, h4, l4) { _Pragma("unroll") \
    for (int i = 0; i < 4; ++i){ const int q = tid + i*256, row = q >> 3, gk = q & 7; \
      const int phys = gk ^ (row & 7); \
      *(uint4*)&BH[buf][row*64 + phys*8] = (h4)[i]; \
      *(uint4*)&BL[buf][row*64 + phys*8] = (l4)[i]; } }
  #define LD_A(c, dst) { _Pragma("unroll") \
    for (int tm = 0; tm < 4; ++tm){ _Pragma("unroll") \
      for (int ks = 0; ks < 2; ++ks) \
        (dst)[tm][ks] = *(const uint4*)(gp[tm] + (size_t)(c)*64 + ks*32); } }

  f32x4 acc[4][4];
  #pragma unroll
  for (int a = 0; a < 4; ++a)
    #pragma unroll
    for (int b = 0; b < 4; ++b) acc[a][b] = (f32x4){0.f,0.f,0.f,0.f};

  uint4 pbh[4], pbl[4];
  uint4 ar[2][4][2];
  LD_B(0, pbh, pbl); ST_B(0, pbh, pbl);
  LD_A(0, ar[0]);
  LD_A(1, ar[1]);
  LD_B(1, pbh, pbl);
  __syncthreads();

  for (int c = 0; c < 64; ++c){
    const int cur = c & 1;
    #pragma unroll
    for (int ks = 0; ks < 2; ++ks){
      U16x8 bh[4], bl[4];
      #pragma unroll
      for (int tn = 0; tn < 4; ++tn){
        const int row = wn*64 + tn*16 + l16;
        const int gk = ks*4 + quad;
        const int phys = gk ^ (row & 7);
        bh[tn].u4 = *(const uint4*)&BH[cur][row*64 + phys*8];
        bl[tn].u4 = *(const uint4*)&BL[cur][row*64 + phys*8];
      }
      #pragma unroll
      for (int tm = 0; tm < 4; ++tm){
        U16x8 a; a.u4 = ar[cur][tm][ks];
        #pragma unroll
        for (int tn = 0; tn < 4; ++tn){
          acc[tm][tn] = MFMA16(a, bh[tn], acc[tm][tn]);
          acc[tm][tn] = MFMA16(a, bl[tn], acc[tm][tn]);
        }
      }
    }
    if (c + 2 < 64) LD_A(c+2, ar[cur]);
    if (c + 1 < 64){
      ST_B(cur ^ 1, pbh, pbl);
      if (c + 2 < 64) LD_B(c+2, pbh, pbl);
      __syncthreads();
    }
  }
  #pragma unroll
  for (int tm = 0; tm < 4; ++tm){
    #pragma unroll
    for (int tn = 0; tn < 4; ++tn){
      const int p = n0 + wn*64 + tn*16 + l16;
      #pragma unroll
      for (int r = 0; r < 4; ++r){
        const int rm = m0 + wm*64 + tm*16 + quad*4 + r;
        out[((size_t)(rm & 63)*128 + (rm >> 6))*512 + p] = acc[tm][tn][r];
      }
    }
  }
}

extern "C" void kernel_launch(void* const* d_in, const int* in_sizes, int n_in,
                              void* d_out, int out_size, void* d_ws, size_t ws_size,
                              hipStream_t stream) {
  const float* v    = (const float*)d_in[0];
  const float* p0   = (const float*)d_in[1];
  const float* Wini = (const float*)d_in[2];
  const float* Wih  = (const float*)d_in[3];
  const float* Whh  = (const float*)d_in[4];
  const float* Wdec = (const float*)d_in[5];
  float* out = (float*)d_out;
  char* wsb = (char*)d_ws;

  // ws layout (bytes)
  unsigned int*   bar  = (unsigned int*)(wsb + 0);          // 16 KB (flags)
  unsigned short* hHiA = (unsigned short*)(wsb + 16384);
  unsigned short* hLoA = (unsigned short*)(wsb + 540672);
  unsigned short* hHiB = (unsigned short*)(wsb + 1064960);
  unsigned short* hLoB = (unsigned short*)(wsb + 1589248);
  float*          part = (float*)(wsb + 2113536);           // 16 MB = [2][256][8192] f32
  unsigned short* WdH  = (unsigned short*)(wsb + 18890752); // 4 MB
  unsigned short* WdL  = (unsigned short*)(wsb + 23085056); // 4 MB
  unsigned short* G    = (unsigned short*)(wsb + 27279360); // 64 MB
  // end ~94.4 MB

  hipMemsetAsync(bar, 0, 16384, stream);
  split_fp32<<<dim3(2048), dim3(256), 0, stream>>>(Wdec, WdH, WdL, 524288);
  h0_mm<<<dim3(32), dim3(512), 0, stream>>>(p0, Wini, hHiA, hLoA);
  rnn_persist<<<dim3(256), dim3(512), 0, stream>>>(Whh, v, Wih,
                                                   hHiA, hLoA, hHiB, hLoB,
                                                   part, bar, G);
  decode_g<<<dim3(64, 4), dim3(256), 0, stream>>>(G, WdH, WdL, out);
}

// Round 8
// 2532.130 us; speedup vs baseline: 2.0674x; 1.0256x over previous
//
#include <hip/hip_runtime.h>

typedef __attribute__((ext_vector_type(8))) short short8;
typedef __attribute__((ext_vector_type(4))) float f32x4;
union U16x8 { uint4 u4; short8 s8; };

__device__ inline float bf2f(unsigned short u){
  unsigned int x = ((unsigned int)u) << 16;
  float f; __builtin_memcpy(&f, &x, 4); return f;
}
__device__ inline unsigned short f2bf(float f){
  unsigned int x; __builtin_memcpy(&x, &f, 4);
  x = x + 0x7FFFu + ((x >> 16) & 1u);
  return (unsigned short)(x >> 16);
}
__device__ inline void split4(float4 f, uint2& hi, uint2& lo){
  unsigned short h0=f2bf(f.x), h1=f2bf(f.y), h2=f2bf(f.z), h3=f2bf(f.w);
  unsigned short l0=f2bf(f.x-bf2f(h0)), l1=f2bf(f.y-bf2f(h1)),
                 l2=f2bf(f.z-bf2f(h2)), l3=f2bf(f.w-bf2f(h3));
  hi = (uint2){(unsigned)h0 | ((unsigned)h1<<16), (unsigned)h2 | ((unsigned)h3<<16)};
  lo = (uint2){(unsigned)l0 | ((unsigned)l1<<16), (unsigned)l2 | ((unsigned)l3<<16)};
}
__device__ inline void split8(float4 f0, float4 f1, uint4& hi, uint4& lo){
  uint2 h0,l0,h1,l1; split4(f0,h0,l0); split4(f1,h1,l1);
  hi = (uint4){h0.x,h0.y,h1.x,h1.y};
  lo = (uint4){l0.x,l0.y,l1.x,l1.y};
}

#define MFMA16(a,b,c) __builtin_amdgcn_mfma_f32_16x16x32_bf16((a).s8,(b).s8,(c),0,0,0)

// device-scope (sc1) fine-grained ops — cross-XCD coherent without cache flushes
__device__ inline void st_f32_sc(float* p, float v){
  __hip_atomic_store(p, v, __ATOMIC_RELAXED, __HIP_MEMORY_SCOPE_AGENT);
}
__device__ inline void st_u32_sc(unsigned int* p, unsigned int v){
  __hip_atomic_store(p, v, __ATOMIC_RELAXED, __HIP_MEMORY_SCOPE_AGENT);
}
__device__ inline unsigned long long ld_u64_sc(const unsigned long long* p){
  return __hip_atomic_load(p, __ATOMIC_RELAXED, __HIP_MEMORY_SCOPE_AGENT);
}
__device__ inline uint4 ld_b128_sc(const unsigned short* p){
  uint4 r;
  asm volatile("global_load_dwordx4 %0, %1, off sc0 sc1"
               : "=&v"(r) : "v"(p) : "memory");
  return r;
}
__device__ inline unsigned int poll_flag(const unsigned int* p){
  unsigned int r;
  asm volatile("global_load_dword %0, %1, off sc0 sc1\n\ts_waitcnt vmcnt(0)"
               : "=&v"(r) : "v"(p) : "memory");
  return r;
}
__device__ inline void wait_vm0(){ asm volatile("s_waitcnt vmcnt(0)" ::: "memory"); }

__global__ __launch_bounds__(256)
void split_fp32(const float* __restrict__ x,
                unsigned short* __restrict__ hi,
                unsigned short* __restrict__ lo, int n4){
  int i = blockIdx.x * 256 + threadIdx.x;
  if (i >= n4) return;
  float4 v = ((const float4*)x)[i];
  ushort4 h, l;
  h.x = f2bf(v.x); l.x = f2bf(v.x - bf2f(h.x));
  h.y = f2bf(v.y); l.y = f2bf(v.y - bf2f(h.y));
  h.z = f2bf(v.z); l.z = f2bf(v.z - bf2f(h.z));
  h.w = f2bf(v.w); l.w = f2bf(v.w - bf2f(h.w));
  ((ushort4*)hi)[i] = h;
  ((ushort4*)lo)[i] = l;
}

// h0 = p0(64x512) @ Winit(4096x512)^T, 3-term. Writes h in SWIZZLED global layout.
__global__ __launch_bounds__(512, 2)
void h0_mm(const float* __restrict__ p0,
           const float* __restrict__ Wini,
           unsigned short* __restrict__ oHi,
           unsigned short* __restrict__ oLo)
{
  const int nb = blockIdx.x;
  const int tid = threadIdx.x, lane = tid & 63, wave = tid >> 6;
  const int quad = lane >> 4, l16 = lane & 15;
  const int mw = wave & 3, nw = wave >> 2;
  __shared__ __attribute__((aligned(16))) unsigned short BH[128*40];
  __shared__ __attribute__((aligned(16))) unsigned short BL[128*40];
  const int srow = tid >> 2, sk = (tid & 3) << 3;
  const float* wp = Wini + (size_t)(nb*128 + srow)*512 + sk;
  const float* ap = p0 + (size_t)(mw*16 + l16)*512 + quad*8;
  f32x4 acc[4];
  #pragma unroll
  for (int tn = 0; tn < 4; ++tn) acc[tn] = (f32x4){0.f,0.f,0.f,0.f};
  for (int kc = 0; kc < 16; ++kc){
    float4 f0 = *(const float4*)(wp + kc*32);
    float4 f1 = *(const float4*)(wp + kc*32 + 4);
    uint4 hi, lo; split8(f0, f1, hi, lo);
    __syncthreads();
    *(uint4*)&BH[srow*40 + sk] = hi;
    *(uint4*)&BL[srow*40 + sk] = lo;
    __syncthreads();
    float4 a0 = *(const float4*)(ap + kc*32);
    float4 a1 = *(const float4*)(ap + kc*32 + 4);
    uint4 ahi, alo; split8(a0, a1, ahi, alo);
    U16x8 aU, lU; aU.u4 = ahi; lU.u4 = alo;
    #pragma unroll
    for (int tn = 0; tn < 4; ++tn){
      U16x8 bh, bl;
      const int off = (nw*64 + tn*16 + l16)*40 + quad*8;
      bh.u4 = *(const uint4*)&BH[off];
      bl.u4 = *(const uint4*)&BL[off];
      acc[tn] = MFMA16(aU, bh, acc[tn]);
      acc[tn] = MFMA16(aU, bl, acc[tn]);
      acc[tn] = MFMA16(lU, bh, acc[tn]);
    }
  }
  #pragma unroll
  for (int tn = 0; tn < 4; ++tn){
    const int n = nb*128 + nw*64 + tn*16 + l16;
    #pragma unroll
    for (int r = 0; r < 4; ++r){
      const int row = mw*16 + quad*4 + r;
      const int g = n >> 3, gp = (g & ~7) | ((g & 7) ^ (row & 7));
      const int np = (gp << 3) | (n & 7);
      float val = acc[tn][r];
      unsigned short hh = f2bf(val);
      oHi[(size_t)row*4096 + np] = hh;
      oLo[(size_t)row*4096 + np] = f2bf(val - bf2f(hh));
    }
  }
}

// Persistent RNN: 256 blocks (kb=bx&7, nb=bx>>3) x 512 thr. W hi/lo in VGPRs.
// r8 = r6 (verified 2597us) + two minimal edits:
//  (1) start-wait polls ONLY A-row producers (lanes 0..31); the B-producer wait
//      (lanes 32..63) moves to just before stage-B load issue (~30% into the
//      step). Pure delay of an existing wait (no flags set between old and new
//      position) -> deadlock-free relative to r6; WAR chain re-closes because
//      pA is still set after wait-B in program order.
//  (2) the G store (consumed only by decode_g after kernel end) is issued AFTER
//      the h-store drain, so h-publish -> prodDone no longer waits on it.
// Everything else byte-identical to r6. Flags: pA[bx]=bar[bx*4],
// pB[bx]=bar[1024+bx*4], prodDone[bx]=bar[2048+bx*4]; monotone single-writer;
// part double-buffered [2][256][8192].
__global__ __launch_bounds__(512, 2)
void rnn_persist(const float* __restrict__ W,
                 const float* __restrict__ v,
                 const float* __restrict__ Wih,
                 unsigned short* __restrict__ hHiA,
                 unsigned short* __restrict__ hLoA,
                 unsigned short* __restrict__ hHiB,
                 unsigned short* __restrict__ hLoB,
                 float* __restrict__ part,
                 unsigned int* __restrict__ bar,
                 unsigned short* __restrict__ G)
{
  const int bx = blockIdx.x, kb = bx & 7, nb = bx >> 3;
  const int tid = threadIdx.x, lane = tid & 63, wave = tid >> 6;
  const int quad = lane >> 4, l16 = lane & 15;
  __shared__ __attribute__((aligned(16))) unsigned short AH[32*512];  // 32 KB
  __shared__ __attribute__((aligned(16))) unsigned short AL[32*512];  // 32 KB

  unsigned int* pA       = bar;          // [256], stride 4 dwords
  unsigned int* pB       = bar + 1024;   // [256], stride 4 dwords
  unsigned int* prodDone = bar + 2048;   // [256], stride 4 dwords

  // W slice -> registers: wave owns 16 cols (nb*128 + wave*16 + l16), k-slice kb*512
  uint4 whi[16], wlo[16];
  {
    const float* wp = W + (size_t)(nb*128 + wave*16 + l16)*4096 + kb*512 + quad*8;
    #pragma unroll
    for (int c = 0; c < 16; ++c){
      float4 f0 = *(const float4*)(wp + c*32);
      float4 f1 = *(const float4*)(wp + c*32 + 4);
      split8(f0, f1, whi[c], wlo[c]);
    }
  }

  const int redM = bx >> 2;                 // row this block reduces (0..63)
  const int nbase = ((bx & 3) << 10) + (tid << 1);
  const int cR = kb >> 1;                   // col-quarter class of stage slice
  const bool aRed = (bx < 128);             // redM < 32  <=>  group-A reducer
  const float4 wi = *(const float4*)(Wih + (size_t)nbase*2);  // step-invariant

  for (int s = 0; s < 128; ++s){
    const unsigned short* hH = (s & 1) ? hHiB : hHiA;
    const unsigned short* hL = (s & 1) ? hLoB : hLoA;
    unsigned short* nHi = (s & 1) ? hHiA : hHiB;
    unsigned short* nLo = (s & 1) ? hLoA : hLoB;
    float* pbuf = part + (size_t)(s & 1) * 2097152;   // [256][8192] f32

    // ---- start-wait: A-row producers only (rows 0..31) ----
    if (s > 0){
      if (tid < 32){
        const unsigned int* f = prodDone + (tid*4 + cR)*4;
        while ((int)poll_flag(f) < s) __builtin_amdgcn_s_sleep(1);
      }
      __syncthreads();
    }

    // ---- stage group A (rows 0..31), k-slice kb ----
    {
      uint4 stg[8];
      #pragma unroll
      for (int i = 0; i < 4; ++i){
        const int flat = tid + i*512, row = flat >> 6, g = flat & 63;
        stg[i]     = ld_b128_sc(hH + (size_t)row*4096 + (kb << 9) + g*8);
        stg[4 + i] = ld_b128_sc(hL + (size_t)row*4096 + (kb << 9) + g*8);
      }
      wait_vm0();
      #pragma unroll
      for (int i = 0; i < 4; ++i){
        const int flat = tid + i*512, row = flat >> 6, g = flat & 63;
        *(uint4*)&AH[row*512 + g*8] = stg[i];
        *(uint4*)&AL[row*512 + g*8] = stg[4 + i];
      }
    }
    __syncthreads();

    // ---- wait-B: B-row producers (rows 32..63), just before B load issue ----
    if (s > 0){
      if (tid >= 32 && tid < 64){
        const unsigned int* f = prodDone + (tid*4 + cR)*4;
        while ((int)poll_flag(f) < s) __builtin_amdgcn_s_sleep(1);
      }
      __syncthreads();
    }

    // ---- issue group-B stage loads (rows 32..63); fly under mfmaA ----
    uint4 stgB[8];
    #pragma unroll
    for (int i = 0; i < 4; ++i){
      const int flat = tid + i*512, row = 32 + (flat >> 6), g = flat & 63;
      stgB[i]     = ld_b128_sc(hH + (size_t)row*4096 + (kb << 9) + g*8);
      stgB[4 + i] = ld_b128_sc(hL + (size_t)row*4096 + (kb << 9) + g*8);
    }

    // ---- mfma A: 16 k-chunks x 2 m-tiles x 3 terms ----
    {
      f32x4 a0[2], a1[2], a2[2];
      #pragma unroll
      for (int mt = 0; mt < 2; ++mt){
        a0[mt] = (f32x4){0.f,0.f,0.f,0.f};
        a1[mt] = (f32x4){0.f,0.f,0.f,0.f};
        a2[mt] = (f32x4){0.f,0.f,0.f,0.f};
      }
      #pragma unroll
      for (int c = 0; c < 16; ++c){
        U16x8 bh, bl; bh.u4 = whi[c]; bl.u4 = wlo[c];
        #pragma unroll
        for (int mt = 0; mt < 2; ++mt){
          const int row = mt*16 + l16;
          const int gk = c*4 + quad;
          const int phys = (gk & 56) | ((gk & 7) ^ (row & 7));
          U16x8 ah, al;
          ah.u4 = *(const uint4*)&AH[row*512 + phys*8];
          al.u4 = *(const uint4*)&AL[row*512 + phys*8];
          a0[mt] = MFMA16(ah, bh, a0[mt]);
          a1[mt] = MFMA16(ah, bl, a1[mt]);
          a2[mt] = MFMA16(al, bh, a2[mt]);
        }
      }
      // ---- store A partials (rows 0..31 of tile) ----
      float* pb = pbuf + (size_t)bx*8192 + wave*1024 + l16;
      #pragma unroll
      for (int mt = 0; mt < 2; ++mt)
        #pragma unroll
        for (int r = 0; r < 4; ++r)
          st_f32_sc(pb + (mt*16 + quad*4 + r)*16, a0[mt][r] + a1[mt][r] + a2[mt][r]);
    }
    wait_vm0();          // drains B stage loads AND A partial stores
    __syncthreads();     // all waves: stores retired, mfmaA LDS reads done
    if (tid == 0) st_u32_sc(&pA[bx*4], (unsigned)(s + 1));

    // ---- LDS B (reuse AH/AL) ----
    #pragma unroll
    for (int i = 0; i < 4; ++i){
      const int flat = tid + i*512, row = flat >> 6, g = flat & 63;
      *(uint4*)&AH[row*512 + g*8] = stgB[i];
      *(uint4*)&AL[row*512 + g*8] = stgB[4 + i];
    }
    __syncthreads();

    // ---- mfma B ----
    {
      f32x4 a0[2], a1[2], a2[2];
      #pragma unroll
      for (int mt = 0; mt < 2; ++mt){
        a0[mt] = (f32x4){0.f,0.f,0.f,0.f};
        a1[mt] = (f32x4){0.f,0.f,0.f,0.f};
        a2[mt] = (f32x4){0.f,0.f,0.f,0.f};
      }
      #pragma unroll
      for (int c = 0; c < 16; ++c){
        U16x8 bh, bl; bh.u4 = whi[c]; bl.u4 = wlo[c];
        #pragma unroll
        for (int mt = 0; mt < 2; ++mt){
          const int row = mt*16 + l16;            // local row; row&7 == global&7
          const int gk = c*4 + quad;
          const int phys = (gk & 56) | ((gk & 7) ^ (row & 7));
          U16x8 ah, al;
          ah.u4 = *(const uint4*)&AH[row*512 + phys*8];
          al.u4 = *(const uint4*)&AL[row*512 + phys*8];
          a0[mt] = MFMA16(ah, bh, a0[mt]);
          a1[mt] = MFMA16(ah, bl, a1[mt]);
          a2[mt] = MFMA16(al, bh, a2[mt]);
        }
      }
      // ---- store B partials (rows 32..63 of tile) ----
      float* pb = pbuf + (size_t)bx*8192 + wave*1024 + l16;
      #pragma unroll
      for (int mt = 0; mt < 2; ++mt)
        #pragma unroll
        for (int r = 0; r < 4; ++r)
          st_f32_sc(pb + (32 + mt*16 + quad*4 + r)*16, a0[mt][r] + a1[mt][r] + a2[mt][r]);
    }
    wait_vm0();
    __syncthreads();
    if (tid == 0) st_u32_sc(&pB[bx*4], (unsigned)(s + 1));

    // ---- wait: exact 64 partial tiles of OWN group, then reduce ----
    if (tid < 64){
      const unsigned int* f = (aRed ? pA : pB) + ((bx & 3)*64 + tid)*4;
      while ((int)poll_flag(f) < s + 1) __builtin_amdgcn_s_sleep(1);
    }
    __syncthreads();

    // ---- distributed reduce: 2 elems/thread (row redM, cols nbase, nbase+1) ----
    {
      float2 sum = {0.f, 0.f};
      const size_t off = (size_t)((nbase >> 4) & 7)*1024 + redM*16 + (nbase & 15);
      #pragma unroll
      for (int k2 = 0; k2 < 8; ++k2){
        unsigned long long q = ld_u64_sc((const unsigned long long*)
            (pbuf + (size_t)((nbase >> 7)*8 + k2)*8192 + off));
        float2 p; __builtin_memcpy(&p, &q, 8);
        sum.x += p.x; sum.y += p.y;
      }
      const float2 vv = *(const float2*)(v + ((size_t)redM*128 + s)*2);
      float v0 = fmaxf(sum.x + vv.x*wi.x + vv.y*wi.y, 0.f);
      float v1 = fmaxf(sum.y + vv.x*wi.z + vv.y*wi.w, 0.f);
      const unsigned short h0 = f2bf(v0), h1 = f2bf(v1);
      const unsigned short q0 = f2bf(v0 - bf2f(h0)), q1 = f2bf(v1 - bf2f(h1));
      const int g = nbase >> 3, gp = (g & ~7) | ((g & 7) ^ (redM & 7));
      const int np = (gp << 3) | (nbase & 7);
      st_u32_sc((unsigned int*)(nHi + (size_t)redM*4096 + np),
                (unsigned)h0 | ((unsigned)h1 << 16));
      st_u32_sc((unsigned int*)(nLo + (size_t)redM*4096 + np),
                (unsigned)q0 | ((unsigned)q1 << 16));
      wait_vm0();        // drain h stores only — G store issued after
      __builtin_nontemporal_store((unsigned)h0 | ((unsigned)h1 << 16),
          (unsigned int*)(G + (size_t)s*262144 + (size_t)redM*4096 + nbase));
    }
    __syncthreads();
    if (tid == 0) st_u32_sc(&prodDone[bx*4], (unsigned)(s + 1));
  }
}

// out = G(8192 x 4096, hi-only) @ Wdec(512x4096)^T, 2-term (pre-split bf16).
__global__ __launch_bounds__(256, 1)
void decode_g(const unsigned short* __restrict__ G,
              const unsigned short* __restrict__ WdH,
              const unsigned short* __restrict__ WdL,
              float* __restrict__ out)
{
  const int tid = threadIdx.x, lane = tid & 63, wave = tid >> 6;
  const int quad = lane >> 4, l16 = lane & 15;
  const int wm = wave & 1, wn = wave >> 1;
  const int m0 = blockIdx.x * 128;
  const int n0 = blockIdx.y * 128;
  __shared__ __attribute__((aligned(16))) unsigned short BH[2][128*64];
  __shared__ __attribute__((aligned(16))) unsigned short BL[2][128*64];

  const unsigned short* gp[4];
  #pragma unroll
  for (int tm = 0; tm < 4; ++tm)
    gp[tm] = G + (size_t)(m0 + wm*64 + tm*16 + l16)*4096 + quad*8;

  #define LD_B(c, h4, l4) { _Pragma("unroll") \
    for (int i = 0; i < 4; ++i){ const int q = tid + i*256, row = q >> 3, gk = q & 7; \
      const size_t so = (size_t)(n0 + row)*4096 + (size_t)(c)*64 + gk*8; \
      (h4)[i] = *(const uint4*)(WdH + so); (l4)[i] = *(const uint4*)(WdL + so); } }
  #define ST_B(buf, h4, l4) { _Pragma("unroll") \
    for (int i = 0; i < 4; ++i){ const int q = tid + i*256, row = q >> 3, gk = q & 7; \
      const int phys = gk ^ (row & 7); \
      *(uint4*)&BH[buf][row*64 + phys*8] = (h4)[i]; \
      *(uint4*)&BL[buf][row*64 + phys*8] = (l4)[i]; } }
  #define LD_A(c, dst) { _Pragma("unroll") \
    for (int tm = 0; tm < 4; ++tm){ _Pragma("unroll") \
      for (int ks = 0; ks < 2; ++ks) \
        (dst)[tm][ks] = *(const uint4*)(gp[tm] + (size_t)(c)*64 + ks*32); } }

  f32x4 acc[4][4];
  #pragma unroll
  for (int a = 0; a < 4; ++a)
    #pragma unroll
    for (int b = 0; b < 4; ++b) acc[a][b] = (f32x4){0.f,0.f,0.f,0.f};

  uint4 pbh[4], pbl[4];
  uint4 ar[2][4][2];
  LD_B(0, pbh, pbl); ST_B(0, pbh, pbl);
  LD_A(0, ar[0]);
  LD_A(1, ar[1]);
  LD_B(1, pbh, pbl);
  __syncthreads();

  for (int c = 0; c < 64; ++c){
    const int cur = c & 1;
    #pragma unroll
    for (int ks = 0; ks < 2; ++ks){
      U16x8 bh[4], bl[4];
      #pragma unroll
      for (int tn = 0; tn < 4; ++tn){
        const int row = wn*64 + tn*16 + l16;
        const int gk = ks*4 + quad;
        const int phys = gk ^ (row & 7);
        bh[tn].u4 = *(const uint4*)&BH[cur][row*64 + phys*8];
        bl[tn].u4 = *(const uint4*)&BL[cur][row*64 + phys*8];
      }
      #pragma unroll
      for (int tm = 0; tm < 4; ++tm){
        U16x8 a; a.u4 = ar[cur][tm][ks];
        #pragma unroll
        for (int tn = 0; tn < 4; ++tn){
          acc[tm][tn] = MFMA16(a, bh[tn], acc[tm][tn]);
          acc[tm][tn] = MFMA16(a, bl[tn], acc[tm][tn]);
        }
      }
    }
    if (c + 2 < 64) LD_A(c+2, ar[cur]);
    if (c + 1 < 64){
      ST_B(cur ^ 1, pbh, pbl);
      if (c + 2 < 64) LD_B(c+2, pbh, pbl);
      __syncthreads();
    }
  }
  #pragma unroll
  for (int tm = 0; tm < 4; ++tm){
    #pragma unroll
    for (int tn = 0; tn < 4; ++tn){
      const int p = n0 + wn*64 + tn*16 + l16;
      #pragma unroll
      for (int r = 0; r < 4; ++r){
        const int rm = m0 + wm*64 + tm*16 + quad*4 + r;
        out[((size_t)(rm & 63)*128 + (rm >> 6))*512 + p] = acc[tm][tn][r];
      }
    }
  }
}

extern "C" void kernel_launch(void* const* d_in, const int* in_sizes, int n_in,
                              void* d_out, int out_size, void* d_ws, size_t ws_size,
                              hipStream_t stream) {
  const float* v    = (const float*)d_in[0];
  const float* p0   = (const float*)d_in[1];
  const float* Wini = (const float*)d_in[2];
  const float* Wih  = (const float*)d_in[3];
  const float* Whh  = (const float*)d_in[4];
  const float* Wdec = (const float*)d_in[5];
  float* out = (float*)d_out;
  char* wsb = (char*)d_ws;

  // ws layout (bytes)
  unsigned int*   bar  = (unsigned int*)(wsb + 0);          // 16 KB (flags)
  unsigned short* hHiA = (unsigned short*)(wsb + 16384);
  unsigned short* hLoA = (unsigned short*)(wsb + 540672);
  unsigned short* hHiB = (unsigned short*)(wsb + 1064960);
  unsigned short* hLoB = (unsigned short*)(wsb + 1589248);
  float*          part = (float*)(wsb + 2113536);           // 16 MB = [2][256][8192] f32
  unsigned short* WdH  = (unsigned short*)(wsb + 18890752); // 4 MB
  unsigned short* WdL  = (unsigned short*)(wsb + 23085056); // 4 MB
  unsigned short* G    = (unsigned short*)(wsb + 27279360); // 64 MB
  // end ~94.4 MB

  hipMemsetAsync(bar, 0, 16384, stream);
  split_fp32<<<dim3(2048), dim3(256), 0, stream>>>(Wdec, WdH, WdL, 524288);
  h0_mm<<<dim3(32), dim3(512), 0, stream>>>(p0, Wini, hHiA, hLoA);
  rnn_persist<<<dim3(256), dim3(512), 0, stream>>>(Whh, v, Wih,
                                                   hHiA, hLoA, hHiB, hLoB,
                                                   part, bar, G);
  decode_g<<<dim3(64, 4), dim3(256), 0, stream>>>(G, WdH, WdL, out);
}

// Round 9
// 2461.164 us; speedup vs baseline: 2.1270x; 1.0288x over previous
//
#include <hip/hip_runtime.h>

typedef __attribute__((ext_vector_type(8))) short short8;
typedef __attribute__((ext_vector_type(4))) float f32x4;
union U16x8 { uint4 u4; short8 s8; };

__device__ inline float bf2f(unsigned short u){
  unsigned int x = ((unsigned int)u) << 16;
  float f; __builtin_memcpy(&f, &x, 4); return f;
}
__device__ inline unsigned short f2bf(float f){
  unsigned int x; __builtin_memcpy(&x, &f, 4);
  x = x + 0x7FFFu + ((x >> 16) & 1u);
  return (unsigned short)(x >> 16);
}
__device__ inline void split4(float4 f, uint2& hi, uint2& lo){
  unsigned short h0=f2bf(f.x), h1=f2bf(f.y), h2=f2bf(f.z), h3=f2bf(f.w);
  unsigned short l0=f2bf(f.x-bf2f(h0)), l1=f2bf(f.y-bf2f(h1)),
                 l2=f2bf(f.z-bf2f(h2)), l3=f2bf(f.w-bf2f(h3));
  hi = (uint2){(unsigned)h0 | ((unsigned)h1<<16), (unsigned)h2 | ((unsigned)h3<<16)};
  lo = (uint2){(unsigned)l0 | ((unsigned)l1<<16), (unsigned)l2 | ((unsigned)l3<<16)};
}
__device__ inline void split8(float4 f0, float4 f1, uint4& hi, uint4& lo){
  uint2 h0,l0,h1,l1; split4(f0,h0,l0); split4(f1,h1,l1);
  hi = (uint4){h0.x,h0.y,h1.x,h1.y};
  lo = (uint4){l0.x,l0.y,l1.x,l1.y};
}

#define MFMA16(a,b,c) __builtin_amdgcn_mfma_f32_16x16x32_bf16((a).s8,(b).s8,(c),0,0,0)

// device-scope (sc1) fine-grained ops — cross-XCD coherent without cache flushes
__device__ inline void st_f32_sc(float* p, float v){
  __hip_atomic_store(p, v, __ATOMIC_RELAXED, __HIP_MEMORY_SCOPE_AGENT);
}
__device__ inline void st_u32_sc(unsigned int* p, unsigned int v){
  __hip_atomic_store(p, v, __ATOMIC_RELAXED, __HIP_MEMORY_SCOPE_AGENT);
}
__device__ inline unsigned long long ld_u64_sc(const unsigned long long* p){
  return __hip_atomic_load(p, __ATOMIC_RELAXED, __HIP_MEMORY_SCOPE_AGENT);
}
__device__ inline uint4 ld_b128_sc(const unsigned short* p){
  uint4 r;
  asm volatile("global_load_dwordx4 %0, %1, off sc0 sc1"
               : "=&v"(r) : "v"(p) : "memory");
  return r;
}
__device__ inline unsigned int poll_flag(const unsigned int* p){
  unsigned int r;
  asm volatile("global_load_dword %0, %1, off sc0 sc1\n\ts_waitcnt vmcnt(0)"
               : "=&v"(r) : "v"(p) : "memory");
  return r;
}
__device__ inline void wait_vm0(){ asm volatile("s_waitcnt vmcnt(0)" ::: "memory"); }

__global__ __launch_bounds__(256)
void split_fp32(const float* __restrict__ x,
                unsigned short* __restrict__ hi,
                unsigned short* __restrict__ lo, int n4){
  int i = blockIdx.x * 256 + threadIdx.x;
  if (i >= n4) return;
  float4 v = ((const float4*)x)[i];
  ushort4 h, l;
  h.x = f2bf(v.x); l.x = f2bf(v.x - bf2f(h.x));
  h.y = f2bf(v.y); l.y = f2bf(v.y - bf2f(h.y));
  h.z = f2bf(v.z); l.z = f2bf(v.z - bf2f(h.z));
  h.w = f2bf(v.w); l.w = f2bf(v.w - bf2f(h.w));
  ((ushort4*)hi)[i] = h;
  ((ushort4*)lo)[i] = l;
}

// h0 = p0(64x512) @ Winit(4096x512)^T, 3-term. Writes h in SWIZZLED global layout.
__global__ __launch_bounds__(512, 2)
void h0_mm(const float* __restrict__ p0,
           const float* __restrict__ Wini,
           unsigned short* __restrict__ oHi,
           unsigned short* __restrict__ oLo)
{
  const int nb = blockIdx.x;
  const int tid = threadIdx.x, lane = tid & 63, wave = tid >> 6;
  const int quad = lane >> 4, l16 = lane & 15;
  const int mw = wave & 3, nw = wave >> 2;
  __shared__ __attribute__((aligned(16))) unsigned short BH[128*40];
  __shared__ __attribute__((aligned(16))) unsigned short BL[128*40];
  const int srow = tid >> 2, sk = (tid & 3) << 3;
  const float* wp = Wini + (size_t)(nb*128 + srow)*512 + sk;
  const float* ap = p0 + (size_t)(mw*16 + l16)*512 + quad*8;
  f32x4 acc[4];
  #pragma unroll
  for (int tn = 0; tn < 4; ++tn) acc[tn] = (f32x4){0.f,0.f,0.f,0.f};
  for (int kc = 0; kc < 16; ++kc){
    float4 f0 = *(const float4*)(wp + kc*32);
    float4 f1 = *(const float4*)(wp + kc*32 + 4);
    uint4 hi, lo; split8(f0, f1, hi, lo);
    __syncthreads();
    *(uint4*)&BH[srow*40 + sk] = hi;
    *(uint4*)&BL[srow*40 + sk] = lo;
    __syncthreads();
    float4 a0 = *(const float4*)(ap + kc*32);
    float4 a1 = *(const float4*)(ap + kc*32 + 4);
    uint4 ahi, alo; split8(a0, a1, ahi, alo);
    U16x8 aU, lU; aU.u4 = ahi; lU.u4 = alo;
    #pragma unroll
    for (int tn = 0; tn < 4; ++tn){
      U16x8 bh, bl;
      const int off = (nw*64 + tn*16 + l16)*40 + quad*8;
      bh.u4 = *(const uint4*)&BH[off];
      bl.u4 = *(const uint4*)&BL[off];
      acc[tn] = MFMA16(aU, bh, acc[tn]);
      acc[tn] = MFMA16(aU, bl, acc[tn]);
      acc[tn] = MFMA16(lU, bh, acc[tn]);
    }
  }
  #pragma unroll
  for (int tn = 0; tn < 4; ++tn){
    const int n = nb*128 + nw*64 + tn*16 + l16;
    #pragma unroll
    for (int r = 0; r < 4; ++r){
      const int row = mw*16 + quad*4 + r;
      const int g = n >> 3, gp = (g & ~7) | ((g & 7) ^ (row & 7));
      const int np = (gp << 3) | (n & 7);
      float val = acc[tn][r];
      unsigned short hh = f2bf(val);
      oHi[(size_t)row*4096 + np] = hh;
      oLo[(size_t)row*4096 + np] = f2bf(val - bf2f(hh));
    }
  }
}

// Persistent RNN: 256 blocks (kb=bx&7, nb=bx>>3) x 512 thr. W hi/lo in VGPRs.
// r9 delta vs r8 (verified 2532us): reduce-your-own-columns remapping.
//  Block (kb,nb) reduces rows kb*8..+8 x its own cols nb*128..+128: needs only
//  the 8 tiles (kb',nb) sharing its nb -> reduce detect fan-in 64->8. Stage
//  waits poll exactly 16 A-producers (kb'<4) at start + 16 B-producers (kb'>=4)
//  before B-load issue. A-reducers (kb<4) produce only A-rows, so their reduce
//  runs MID-STEP (after pA + LDS-B, plain blocking loads): h_A + prodDone
//  published ~70% of step. B-reducers (kb>=4) keep the end-of-step tail.
//  WAR re-audited: pA is downstream of BOTH stage waits, so the 2-hop closure
//  reaches all 256 blocks; 2-buffer partial skew + h-buffer WAR close as before.
// Flags: pA[bx]=bar[bx*4], pB[bx]=bar[1024+bx*4], prodDone[bx]=bar[2048+bx*4].
__global__ __launch_bounds__(512, 2)
void rnn_persist(const float* __restrict__ W,
                 const float* __restrict__ v,
                 const float* __restrict__ Wih,
                 unsigned short* __restrict__ hHiA,
                 unsigned short* __restrict__ hLoA,
                 unsigned short* __restrict__ hHiB,
                 unsigned short* __restrict__ hLoB,
                 float* __restrict__ part,
                 unsigned int* __restrict__ bar,
                 unsigned short* __restrict__ G)
{
  const int bx = blockIdx.x, kb = bx & 7, nb = bx >> 3;
  const int tid = threadIdx.x, lane = tid & 63, wave = tid >> 6;
  const int quad = lane >> 4, l16 = lane & 15;
  __shared__ __attribute__((aligned(16))) unsigned short AH[32*512];  // 32 KB
  __shared__ __attribute__((aligned(16))) unsigned short AL[32*512];  // 32 KB

  unsigned int* pA       = bar;          // [256], stride 4 dwords
  unsigned int* pB       = bar + 1024;   // [256], stride 4 dwords
  unsigned int* prodDone = bar + 2048;   // [256], stride 4 dwords

  // W slice -> registers: wave owns 16 cols (nb*128 + wave*16 + l16), k-slice kb*512
  uint4 whi[16], wlo[16];
  {
    const float* wp = W + (size_t)(nb*128 + wave*16 + l16)*4096 + kb*512 + quad*8;
    #pragma unroll
    for (int c = 0; c < 16; ++c){
      float4 f0 = *(const float4*)(wp + c*32);
      float4 f1 = *(const float4*)(wp + c*32 + 4);
      split8(f0, f1, whi[c], wlo[c]);
    }
  }

  const bool aRed = (kb < 4);
  const int row_red = kb*8 + (tid >> 6);          // row this thread reduces
  const int c2 = (tid & 63) << 1;                 // col pair within 128-col slice
  const int gcol = nb*128 + c2;                   // global col (even)
  const float4 wi = *(const float4*)(Wih + (size_t)gcol*2);  // step-invariant

  for (int s = 0; s < 128; ++s){
    const unsigned short* hH = (s & 1) ? hHiB : hHiA;
    const unsigned short* hL = (s & 1) ? hLoB : hLoA;
    unsigned short* nHi = (s & 1) ? hHiA : hHiB;
    unsigned short* nLo = (s & 1) ? hLoA : hLoB;
    float* pbuf = part + (size_t)(s & 1) * 2097152;   // [256][8192] f32

    // ---- W1: exact A-row producers of h(s) k-slice kb (16 flags) ----
    if (s > 0){
      if (tid < 16){
        const int bxp = (4*kb + (tid >> 2))*8 + (tid & 3);
        const unsigned int* f = prodDone + bxp*4;
        while ((int)poll_flag(f) < s) __builtin_amdgcn_s_sleep(1);
      }
      __syncthreads();
    }

    // ---- stage group A (rows 0..31), k-slice kb ----
    {
      uint4 stg[8];
      #pragma unroll
      for (int i = 0; i < 4; ++i){
        const int flat = tid + i*512, row = flat >> 6, g = flat & 63;
        stg[i]     = ld_b128_sc(hH + (size_t)row*4096 + (kb << 9) + g*8);
        stg[4 + i] = ld_b128_sc(hL + (size_t)row*4096 + (kb << 9) + g*8);
      }
      wait_vm0();
      #pragma unroll
      for (int i = 0; i < 4; ++i){
        const int flat = tid + i*512, row = flat >> 6, g = flat & 63;
        *(uint4*)&AH[row*512 + g*8] = stg[i];
        *(uint4*)&AL[row*512 + g*8] = stg[4 + i];
      }
    }
    __syncthreads();

    // ---- W2: exact B-row producers (16 flags), just before B load issue ----
    if (s > 0){
      if (tid < 16){
        const int bxp = (4*kb + (tid >> 2))*8 + 4 + (tid & 3);
        const unsigned int* f = prodDone + bxp*4;
        while ((int)poll_flag(f) < s) __builtin_amdgcn_s_sleep(1);
      }
      __syncthreads();
    }

    // ---- issue group-B stage loads (rows 32..63); fly under mfmaA ----
    uint4 stgB[8];
    #pragma unroll
    for (int i = 0; i < 4; ++i){
      const int flat = tid + i*512, row = 32 + (flat >> 6), g = flat & 63;
      stgB[i]     = ld_b128_sc(hH + (size_t)row*4096 + (kb << 9) + g*8);
      stgB[4 + i] = ld_b128_sc(hL + (size_t)row*4096 + (kb << 9) + g*8);
    }

    // ---- mfma A: 16 k-chunks x 2 m-tiles x 3 terms ----
    {
      f32x4 a0[2], a1[2], a2[2];
      #pragma unroll
      for (int mt = 0; mt < 2; ++mt){
        a0[mt] = (f32x4){0.f,0.f,0.f,0.f};
        a1[mt] = (f32x4){0.f,0.f,0.f,0.f};
        a2[mt] = (f32x4){0.f,0.f,0.f,0.f};
      }
      #pragma unroll
      for (int c = 0; c < 16; ++c){
        U16x8 bh, bl; bh.u4 = whi[c]; bl.u4 = wlo[c];
        #pragma unroll
        for (int mt = 0; mt < 2; ++mt){
          const int row = mt*16 + l16;
          const int gk = c*4 + quad;
          const int phys = (gk & 56) | ((gk & 7) ^ (row & 7));
          U16x8 ah, al;
          ah.u4 = *(const uint4*)&AH[row*512 + phys*8];
          al.u4 = *(const uint4*)&AL[row*512 + phys*8];
          a0[mt] = MFMA16(ah, bh, a0[mt]);
          a1[mt] = MFMA16(ah, bl, a1[mt]);
          a2[mt] = MFMA16(al, bh, a2[mt]);
        }
      }
      // ---- store A partials (rows 0..31 of tile) ----
      float* pb = pbuf + (size_t)bx*8192 + wave*1024 + l16;
      #pragma unroll
      for (int mt = 0; mt < 2; ++mt)
        #pragma unroll
        for (int r = 0; r < 4; ++r)
          st_f32_sc(pb + (mt*16 + quad*4 + r)*16, a0[mt][r] + a1[mt][r] + a2[mt][r]);
    }
    wait_vm0();          // drains B stage loads AND A partial stores
    __syncthreads();     // all waves: stores retired, mfmaA LDS reads done
    if (tid == 0) st_u32_sc(&pA[bx*4], (unsigned)(s + 1));

    // ---- LDS B (reuse AH/AL) ----
    #pragma unroll
    for (int i = 0; i < 4; ++i){
      const int flat = tid + i*512, row = flat >> 6, g = flat & 63;
      *(uint4*)&AH[row*512 + g*8] = stgB[i];
      *(uint4*)&AL[row*512 + g*8] = stgB[4 + i];
    }
    __syncthreads();

    // ---- A-reducers: mid-step reduce of rows kb*8..+8 (fan-in 8) ----
    if (aRed){
      if (tid < 8){
        const unsigned int* f = pA + (nb*8 + tid)*4;
        while ((int)poll_flag(f) < s + 1) __builtin_amdgcn_s_sleep(1);
      }
      __syncthreads();
      {
        const float* base = pbuf + (size_t)(c2 >> 4)*1024 + row_red*16 + (c2 & 15);
        float2 sum = {0.f, 0.f};
        #pragma unroll
        for (int j = 0; j < 8; ++j){
          unsigned long long q = ld_u64_sc((const unsigned long long*)
              (base + (size_t)(nb*8 + j)*8192));
          float2 p; __builtin_memcpy(&p, &q, 8);
          sum.x += p.x; sum.y += p.y;
        }
        const float2 vv = *(const float2*)(v + ((size_t)row_red*128 + s)*2);
        float v0 = fmaxf(sum.x + vv.x*wi.x + vv.y*wi.y, 0.f);
        float v1 = fmaxf(sum.y + vv.x*wi.z + vv.y*wi.w, 0.f);
        const unsigned short h0 = f2bf(v0), h1 = f2bf(v1);
        const unsigned short q0 = f2bf(v0 - bf2f(h0)), q1 = f2bf(v1 - bf2f(h1));
        const int g = gcol >> 3, gp = (g & ~7) | ((g & 7) ^ (row_red & 7));
        const int np = (gp << 3) | (gcol & 7);
        st_u32_sc((unsigned int*)(nHi + (size_t)row_red*4096 + np),
                  (unsigned)h0 | ((unsigned)h1 << 16));
        st_u32_sc((unsigned int*)(nLo + (size_t)row_red*4096 + np),
                  (unsigned)q0 | ((unsigned)q1 << 16));
        wait_vm0();      // drain h stores; G store issued after
        __builtin_nontemporal_store((unsigned)h0 | ((unsigned)h1 << 16),
            (unsigned int*)(G + (size_t)s*262144 + (size_t)row_red*4096 + gcol));
      }
      __syncthreads();
      if (tid == 0) st_u32_sc(&prodDone[bx*4], (unsigned)(s + 1));
    }

    // ---- mfma B ----
    {
      f32x4 a0[2], a1[2], a2[2];
      #pragma unroll
      for (int mt = 0; mt < 2; ++mt){
        a0[mt] = (f32x4){0.f,0.f,0.f,0.f};
        a1[mt] = (f32x4){0.f,0.f,0.f,0.f};
        a2[mt] = (f32x4){0.f,0.f,0.f,0.f};
      }
      #pragma unroll
      for (int c = 0; c < 16; ++c){
        U16x8 bh, bl; bh.u4 = whi[c]; bl.u4 = wlo[c];
        #pragma unroll
        for (int mt = 0; mt < 2; ++mt){
          const int row = mt*16 + l16;            // local row; row&7 == global&7
          const int gk = c*4 + quad;
          const int phys = (gk & 56) | ((gk & 7) ^ (row & 7));
          U16x8 ah, al;
          ah.u4 = *(const uint4*)&AH[row*512 + phys*8];
          al.u4 = *(const uint4*)&AL[row*512 + phys*8];
          a0[mt] = MFMA16(ah, bh, a0[mt]);
          a1[mt] = MFMA16(ah, bl, a1[mt]);
          a2[mt] = MFMA16(al, bh, a2[mt]);
        }
      }
      // ---- store B partials (rows 32..63 of tile) ----
      float* pb = pbuf + (size_t)bx*8192 + wave*1024 + l16;
      #pragma unroll
      for (int mt = 0; mt < 2; ++mt)
        #pragma unroll
        for (int r = 0; r < 4; ++r)
          st_f32_sc(pb + (32 + mt*16 + quad*4 + r)*16, a0[mt][r] + a1[mt][r] + a2[mt][r]);
    }
    wait_vm0();
    __syncthreads();
    if (tid == 0) st_u32_sc(&pB[bx*4], (unsigned)(s + 1));

    // ---- B-reducers: end-of-step reduce of rows kb*8..+8 (fan-in 8) ----
    if (!aRed){
      if (tid < 8){
        const unsigned int* f = pB + (nb*8 + tid)*4;
        while ((int)poll_flag(f) < s + 1) __builtin_amdgcn_s_sleep(1);
      }
      __syncthreads();
      {
        const float* base = pbuf + (size_t)(c2 >> 4)*1024 + row_red*16 + (c2 & 15);
        float2 sum = {0.f, 0.f};
        #pragma unroll
        for (int j = 0; j < 8; ++j){
          unsigned long long q = ld_u64_sc((const unsigned long long*)
              (base + (size_t)(nb*8 + j)*8192));
          float2 p; __builtin_memcpy(&p, &q, 8);
          sum.x += p.x; sum.y += p.y;
        }
        const float2 vv = *(const float2*)(v + ((size_t)row_red*128 + s)*2);
        float v0 = fmaxf(sum.x + vv.x*wi.x + vv.y*wi.y, 0.f);
        float v1 = fmaxf(sum.y + vv.x*wi.z + vv.y*wi.w, 0.f);
        const unsigned short h0 = f2bf(v0), h1 = f2bf(v1);
        const unsigned short q0 = f2bf(v0 - bf2f(h0)), q1 = f2bf(v1 - bf2f(h1));
        const int g = gcol >> 3, gp = (g & ~7) | ((g & 7) ^ (row_red & 7));
        const int np = (gp << 3) | (gcol & 7);
        st_u32_sc((unsigned int*)(nHi + (size_t)row_red*4096 + np),
                  (unsigned)h0 | ((unsigned)h1 << 16));
        st_u32_sc((unsigned int*)(nLo + (size_t)row_red*4096 + np),
                  (unsigned)q0 | ((unsigned)q1 << 16));
        wait_vm0();      // drain h stores; G store issued after
        __builtin_nontemporal_store((unsigned)h0 | ((unsigned)h1 << 16),
            (unsigned int*)(G + (size_t)s*262144 + (size_t)row_red*4096 + gcol));
      }
      __syncthreads();
      if (tid == 0) st_u32_sc(&prodDone[bx*4], (unsigned)(s + 1));
    }
  }
}

// out = G(8192 x 4096, hi-only) @ Wdec(512x4096)^T, 2-term (pre-split bf16).
__global__ __launch_bounds__(256, 1)
void decode_g(const unsigned short* __restrict__ G,
              const unsigned short* __restrict__ WdH,
              const unsigned short* __restrict__ WdL,
              float* __restrict__ out)
{
  const int tid = threadIdx.x, lane = tid & 63, wave = tid >> 6;
  const int quad = lane >> 4, l16 = lane & 15;
  const int wm = wave & 1, wn = wave >> 1;
  const int m0 = blockIdx.x * 128;
  const int n0 = blockIdx.y * 128;
  __shared__ __attribute__((aligned(16))) unsigned short BH[2][128*64];
  __shared__ __attribute__((aligned(16))) unsigned short BL[2][128*64];

  const unsigned short* gp[4];
  #pragma unroll
  for (int tm = 0; tm < 4; ++tm)
    gp[tm] = G + (size_t)(m0 + wm*64 + tm*16 + l16)*4096 + quad*8;

  #define LD_B(c, h4, l4) { _Pragma("unroll") \
    for (int i = 0; i < 4; ++i){ const int q = tid + i*256, row = q >> 3, gk = q & 7; \
      const size_t so = (size_t)(n0 + row)*4096 + (size_t)(c)*64 + gk*8; \
      (h4)[i] = *(const uint4*)(WdH + so); (l4)[i] = *(const uint4*)(WdL + so); } }
  #define ST_B(buf, h4, l4) { _Pragma("unroll") \
    for (int i = 0; i < 4; ++i){ const int q = tid + i*256, row = q >> 3, gk = q & 7; \
      const int phys = gk ^ (row & 7); \
      *(uint4*)&BH[buf][row*64 + phys*8] = (h4)[i]; \
      *(uint4*)&BL[buf][row*64 + phys*8] = (l4)[i]; } }
  #define LD_A(c, dst) { _Pragma("unroll") \
    for (int tm = 0; tm < 4; ++tm){ _Pragma("unroll") \
      for (int ks = 0; ks < 2; ++ks) \
        (dst)[tm][ks] = *(const uint4*)(gp[tm] + (size_t)(c)*64 + ks*32); } }

  f32x4 acc[4][4];
  #pragma unroll
  for (int a = 0; a < 4; ++a)
    #pragma unroll
    for (int b = 0; b < 4; ++b) acc[a][b] = (f32x4){0.f,0.f,0.f,0.f};

  uint4 pbh[4], pbl[4];
  uint4 ar[2][4][2];
  LD_B(0, pbh, pbl); ST_B(0, pbh, pbl);
  LD_A(0, ar[0]);
  LD_A(1, ar[1]);
  LD_B(1, pbh, pbl);
  __syncthreads();

  for (int c = 0; c < 64; ++c){
    const int cur = c & 1;
    #pragma unroll
    for (int ks = 0; ks < 2; ++ks){
      U16x8 bh[4], bl[4];
      #pragma unroll
      for (int tn = 0; tn < 4; ++tn){
        const int row = wn*64 + tn*16 + l16;
        const int gk = ks*4 + quad;
        const int phys = gk ^ (row & 7);
        bh[tn].u4 = *(const uint4*)&BH[cur][row*64 + phys*8];
        bl[tn].u4 = *(const uint4*)&BL[cur][row*64 + phys*8];
      }
      #pragma unroll
      for (int tm = 0; tm < 4; ++tm){
        U16x8 a; a.u4 = ar[cur][tm][ks];
        #pragma unroll
        for (int tn = 0; tn < 4; ++tn){
          acc[tm][tn] = MFMA16(a, bh[tn], acc[tm][tn]);
          acc[tm][tn] = MFMA16(a, bl[tn], acc[tm][tn]);
        }
      }
    }
    if (c + 2 < 64) LD_A(c+2, ar[cur]);
    if (c + 1 < 64){
      ST_B(cur ^ 1, pbh, pbl);
      if (c + 2 < 64) LD_B(c+2, pbh, pbl);
      __syncthreads();
    }
  }
  #pragma unroll
  for (int tm = 0; tm < 4; ++tm){
    #pragma unroll
    for (int tn = 0; tn < 4; ++tn){
      const int p = n0 + wn*64 + tn*16 + l16;
      #pragma unroll
      for (int r = 0; r < 4; ++r){
        const int rm = m0 + wm*64 + tm*16 + quad*4 + r;
        out[((size_t)(rm & 63)*128 + (rm >> 6))*512 + p] = acc[tm][tn][r];
      }
    }
  }
}

extern "C" void kernel_launch(void* const* d_in, const int* in_sizes, int n_in,
                              void* d_out, int out_size, void* d_ws, size_t ws_size,
                              hipStream_t stream) {
  const float* v    = (const float*)d_in[0];
  const float* p0   = (const float*)d_in[1];
  const float* Wini = (const float*)d_in[2];
  const float* Wih  = (const float*)d_in[3];
  const float* Whh  = (const float*)d_in[4];
  const float* Wdec = (const float*)d_in[5];
  float* out = (float*)d_out;
  char* wsb = (char*)d_ws;

  // ws layout (bytes)
  unsigned int*   bar  = (unsigned int*)(wsb + 0);          // 16 KB (flags)
  unsigned short* hHiA = (unsigned short*)(wsb + 16384);
  unsigned short* hLoA = (unsigned short*)(wsb + 540672);
  unsigned short* hHiB = (unsigned short*)(wsb + 1064960);
  unsigned short* hLoB = (unsigned short*)(wsb + 1589248);
  float*          part = (float*)(wsb + 2113536);           // 16 MB = [2][256][8192] f32
  unsigned short* WdH  = (unsigned short*)(wsb + 18890752); // 4 MB
  unsigned short* WdL  = (unsigned short*)(wsb + 23085056); // 4 MB
  unsigned short* G    = (unsigned short*)(wsb + 27279360); // 64 MB
  // end ~94.4 MB

  hipMemsetAsync(bar, 0, 16384, stream);
  split_fp32<<<dim3(2048), dim3(256), 0, stream>>>(Wdec, WdH, WdL, 524288);
  h0_mm<<<dim3(32), dim3(512), 0, stream>>>(p0, Wini, hHiA, hLoA);
  rnn_persist<<<dim3(256), dim3(512), 0, stream>>>(Whh, v, Wih,
                                                   hHiA, hLoA, hHiB, hLoB,
                                                   part, bar, G);
  decode_g<<<dim3(64, 4), dim3(256), 0, stream>>>(G, WdH, WdL, out);
}